// Round 4
// baseline (1078.541 us; speedup 1.0000x reference)
//
#include <hip/hip_runtime.h>
#include <hip/hip_bf16.h>

// G2AAgent — ROUND 4: fp32 outputs (reference output dtype is float32).
// Rounds 2/3 produced bit-identical absmax with MFMA vs VALU GEMMs ->
// both compute the same function (MFMA layout validated); the 3.363 error
// matches the "bf16 written, fp32 decoded" bound (1.13 + 2*1.13 = 3.39).
// Pipeline: bf16 internals + fp32 accumulate, fp32 final stores.

typedef __attribute__((ext_vector_type(8))) short short8;
typedef __attribute__((ext_vector_type(4))) float float4v;

#define BF2F(x) __bfloat162float(x)
typedef __hip_bfloat16 bf;

__device__ __forceinline__ float fsigmoid(float x) {
  return 1.f / (1.f + __expf(-x));
}
__device__ __forceinline__ float ftanh(float x) {
  float ax = fabsf(x);
  float e = __expf(-2.f * ax);
  float t = (1.f - e) / (1.f + e);
  return x < 0.f ? -t : t;
}
// read value at native precision: f=1 -> fp32 buffer, f=0 -> bf16 buffer
__device__ __forceinline__ float rdv(const void* p, int i, int f) {
  return f ? ((const float*)p)[i] : BF2F(((const bf*)p)[i]);
}

// ---------------------------------------------------------------------------
// bf16 arena: element offsets/counts for the 23 inputs (16B-aligned offsets).
static const int AO[23] = {
  0, 2097152, 4194304, 4685824, 4702208, 4702336, 4751488, 4800640, 4801024,
  4801408, 4899712, 4948864, 4949248, 4949632, 5047936, 5097088, 5097472,
  5097856, 5098368, 5098384, 5102480, 5106576, 5110160};
static const int AN[23] = {
  2097152, 2097152, 491520, 16384, 128, 49152, 49152, 384, 384, 98304, 49152,
  384, 384, 98304, 49152, 384, 384, 512, 2, 4096, 4096, 3584, 14};

struct CArgs {
  const void* src[23];
  int n[23];
  int off[23];
};

// kDetect: fp32 (flag=1) vs bf16 (flag=0) by exponent histogram of d_in[0]
// reinterpreted as bf16. fp32 mantissa halves -> uniform exponents, ~25% hit
// >=0xC0; true bf16 N(0,1) never does.
__global__ void kDetect(const unsigned short* __restrict__ p, int* flag) {
  __shared__ int s;
  if (threadIdx.x == 0) s = 0;
  __syncthreads();
  int hit = 0;
  for (int i = threadIdx.x; i < 4096; i += 1024) {
    int e = (p[i] >> 7) & 0xFF;
    if (e >= 0xC0) hit = 1;
  }
  if (hit) atomicOr(&s, 1);
  __syncthreads();
  if (threadIdx.x == 0) *flag = s;
}

// kConvert: every input -> bf16 arena (cvt if fp32, raw copy if bf16).
__global__ void kConvert(CArgs a, const int* __restrict__ flag,
                         bf* __restrict__ arena) {
  const int b = blockIdx.y;
  const int n = a.n[b];
  const int f = *flag;
  bf* dst = arena + a.off[b];
  if (f) {
    const float* s = (const float*)a.src[b];
    for (int i = blockIdx.x * 256 + threadIdx.x; i < n; i += gridDim.x * 256)
      dst[i] = __float2bfloat16(s[i]);
  } else {
    const unsigned short* s = (const unsigned short*)a.src[b];
    unsigned short* d = (unsigned short*)dst;
    for (int i = blockIdx.x * 256 + threadIdx.x; i < n; i += gridDim.x * 256)
      d[i] = s[i];
  }
}

// ---------------------------------------------------------------------------
// kPrep: build Wcat (1600x128) + bcat (1600) from arena weights.
// Rows: [f_self(384); f_nbr(384); b_self(384); b_nbr(384); Wq(32); Wk(32)]
__global__ void kPrep(const bf* __restrict__ Wih_f, const bf* __restrict__ bih_f,
                      const bf* __restrict__ Wih_b, const bf* __restrict__ bih_b,
                      const bf* __restrict__ Wq, const bf* __restrict__ Wk,
                      bf* __restrict__ Wcat, bf* __restrict__ bcat) {
  int idx = blockIdx.x * 256 + threadIdx.x;
  if (idx < 1600 * 128) {
    int r = idx >> 7, c = idx & 127;
    bf v;
    if (r < 384)       v = Wih_f[r * 256 + c];
    else if (r < 768)  v = Wih_f[(r - 384) * 256 + 128 + c];
    else if (r < 1152) v = Wih_b[(r - 768) * 256 + c];
    else if (r < 1536) v = Wih_b[(r - 1152) * 256 + 128 + c];
    else if (r < 1568) v = Wq[(r - 1536) * 128 + c];
    else               v = Wk[(r - 1568) * 128 + c];
    Wcat[idx] = v;
  }
  if (idx < 1600) {
    bf bv = __float2bfloat16(0.f);
    if (idx < 384) bv = bih_f[idx];
    else if (idx >= 768 && idx < 1152) bv = bih_b[idx - 768];
    bcat[idx] = bv;
  }
}

// ---------------------------------------------------------------------------
// kGemm: out[M x N](bf16) = A[M x 128] @ W[N x 128]^T + bias, optional relu.
// MFMA 16x16x32 bf16; A-frag row=lane&15, k=quad*8+j; C/D col=lane&15,
// row=quad*4+reg (validated: MFMA and VALU builds agreed bit-identically).
__global__ __launch_bounds__(256) void kGemm(const bf* __restrict__ A,
                                             const bf* __restrict__ W,
                                             const bf* __restrict__ bias,
                                             bf* __restrict__ out,
                                             int N, int relu) {
  const int tid = threadIdx.x;
  const int wave = tid >> 6, lane = tid & 63;
  const int quad = lane >> 4, ci = lane & 15;
  const int mr = blockIdx.x * 64 + wave * 16;
  const int nbase = blockIdx.y * 64;

  float4v acc[4];
#pragma unroll
  for (int i = 0; i < 4; ++i) acc[i] = {0.f, 0.f, 0.f, 0.f};

#pragma unroll
  for (int ks = 0; ks < 4; ++ks) {
    short8 a = *(const short8*)(A + (size_t)(mr + ci) * 128 + ks * 32 + quad * 8);
#pragma unroll
    for (int nt = 0; nt < 4; ++nt) {
      short8 b = *(const short8*)(W + (size_t)(nbase + nt * 16 + ci) * 128 + ks * 32 + quad * 8);
      acc[nt] = __builtin_amdgcn_mfma_f32_16x16x32_bf16(a, b, acc[nt], 0, 0, 0);
    }
  }

#pragma unroll
  for (int nt = 0; nt < 4; ++nt) {
    int col = nbase + nt * 16 + ci;
    float bv = bias ? BF2F(bias[col]) : 0.f;
#pragma unroll
    for (int r = 0; r < 4; ++r) {
      int row = mr + quad * 4 + r;
      float v = acc[nt][r] + bv;
      if (relu) v = fmaxf(v, 0.f);
      out[(size_t)row * N + col] = __float2bfloat16(v);
    }
  }
}

// ---------------------------------------------------------------------------
// kStep: one GRU step (cell mode: has_nbr=0, grid.y=1).
// gh = Hp @ Whh^T via MFMA (N=384,K=128); gi gathered from G; gates fused.
// WcRaw!=null -> partial logits (fp32 Wc at native precision) -> L.
// HcopyF!=null -> fp32 duplicate of h into d_out (h_rnn output).
__global__ __launch_bounds__(256, 2) void kStep(
    const bf* __restrict__ Hp0, const bf* __restrict__ Hp1,
    const bf* __restrict__ Whh0, const bf* __restrict__ Whh1,
    const bf* __restrict__ G, int gld, int goff0, int goff1,
    int has_nbr, int m0, int m1,
    const bf* __restrict__ bhh0, const bf* __restrict__ bhh1,
    bf* __restrict__ Ho0, bf* __restrict__ Ho1,
    float* __restrict__ HcopyF,
    const void* __restrict__ WcRaw, const int* __restrict__ flagp,
    float* __restrict__ L) {
  const int dir = blockIdx.y;
  const bf* Hp  = dir ? Hp1 : Hp0;
  const bf* Whh = dir ? Whh1 : Whh0;
  const bf* bhh = dir ? bhh1 : bhh0;
  bf* Ho        = dir ? Ho1 : Ho0;
  const int goff = dir ? goff1 : goff0;
  const int m    = dir ? m1 : m0;

  const int tid = threadIdx.x;
  const int wave = tid >> 6, lane = tid & 63;
  const int quad = lane >> 4, ci = lane & 15;
  const int mr = blockIdx.x * 64 + wave * 16;

  float4v acc[24];
#pragma unroll
  for (int i = 0; i < 24; ++i) acc[i] = {0.f, 0.f, 0.f, 0.f};

  if (Hp) {
#pragma unroll
    for (int ks = 0; ks < 4; ++ks) {
      short8 a = *(const short8*)(Hp + (size_t)(mr + ci) * 128 + ks * 32 + quad * 8);
#pragma unroll
      for (int nt = 0; nt < 24; ++nt) {
        short8 b = *(const short8*)(Whh + (size_t)(nt * 16 + ci) * 128 + ks * 32 + quad * 8);
        acc[nt] = __builtin_amdgcn_mfma_f32_16x16x32_bf16(a, b, acc[nt], 0, 0, 0);
      }
    }
  }

  const int wf = flagp ? *flagp : 0;
  float bR[8], bZ[8], bN[8], wc0[8], wc1[8];
#pragma unroll
  for (int nt = 0; nt < 8; ++nt) {
    int c = nt * 16 + ci;
    bR[nt] = BF2F(bhh[c]);
    bZ[nt] = BF2F(bhh[128 + c]);
    bN[nt] = BF2F(bhh[256 + c]);
    if (WcRaw) {
      wc0[nt] = rdv(WcRaw, dir * 128 + c, wf);
      wc1[nt] = rdv(WcRaw, 256 + dir * 128 + c, wf);
    } else {
      wc0[nt] = 0.f; wc1[nt] = 0.f;
    }
  }

#pragma unroll
  for (int r = 0; r < 4; ++r) {
    int rr = mr + quad * 4 + r;
    const bf* gs = G + (size_t)rr * gld + goff;
    const bf* gn = nullptr;
    if (has_nbr) {
      int a_id = rr & 15;
      int j = m + (m >= a_id);
      gn = G + (size_t)((rr & ~15) | j) * gld + goff + 384;
    }
    float pl0 = 0.f, pl1 = 0.f;
#pragma unroll
    for (int nt = 0; nt < 8; ++nt) {
      int c = nt * 16 + ci;
      float gr = BF2F(gs[c]), gz = BF2F(gs[128 + c]), gnn = BF2F(gs[256 + c]);
      if (gn) {
        gr += BF2F(gn[c]); gz += BF2F(gn[128 + c]); gnn += BF2F(gn[256 + c]);
      }
      float pre_r = acc[nt][r] + gr + bR[nt];
      float pre_z = acc[nt + 8][r] + gz + bZ[nt];
      float hn_   = acc[nt + 16][r] + bN[nt];
      float rg = fsigmoid(pre_r);
      float zg = fsigmoid(pre_z);
      float ng = ftanh(gnn + rg * hn_);
      float hp = Hp ? BF2F(Hp[(size_t)rr * 128 + c]) : 0.f;
      float hv = (1.f - zg) * ng + zg * hp;
      Ho[(size_t)rr * 128 + c] = __float2bfloat16(hv);
      if (HcopyF) HcopyF[(size_t)rr * 128 + c] = hv;
      pl0 += hv * wc0[nt];
      pl1 += hv * wc1[nt];
    }
    if (WcRaw) {
#pragma unroll
      for (int d = 1; d < 16; d <<= 1) {
        pl0 += __shfl_xor(pl0, d);
        pl1 += __shfl_xor(pl1, d);
      }
      if (ci == 0) {
        float* Lp = L + (size_t)rr * 60 + m * 4 + dir * 2;
        Lp[0] = pl0;
        Lp[1] = pl1;
      }
    }
  }
}

// ---------------------------------------------------------------------------
// kGumbel: hard_w = sigmoid(((l1+g1)-(l0+g0)) / TAU), TAU=0.5.
__global__ void kGumbel(const float* __restrict__ L, const void* __restrict__ guRaw,
                        const int* __restrict__ flag, const void* __restrict__ bcRaw,
                        float* __restrict__ hw) {
  int idx = blockIdx.x * 256 + threadIdx.x;
  if (idx >= 245760) return;
  const int f = *flag;
  int row = idx / 15, mm = idx - row * 15;
  const float* Lp = L + (size_t)row * 60 + mm * 4;
  float l0 = Lp[0] + Lp[2] + rdv(bcRaw, 0, f);
  float l1 = Lp[1] + Lp[3] + rdv(bcRaw, 1, f);
  float u0 = rdv(guRaw, idx * 2, f);
  float u1 = rdv(guRaw, idx * 2 + 1, f);
  float g0 = -__logf(-__logf(u0 + 1e-10f) + 1e-10f);
  float g1 = -__logf(-__logf(u1 + 1e-10f) + 1e-10f);
  float d = ((l1 + g1) - (l0 + g0)) * 2.0f;
  hw[idx] = fsigmoid(d);
}

// ---------------------------------------------------------------------------
// kAttn: per-env attention + out14 = [h, agg] @ W2^T + b2 (fp32 out).
__global__ __launch_bounds__(256) void kAttn(
    const bf* __restrict__ h, const bf* __restrict__ G, int gld,
    const float* __restrict__ hw, const void* __restrict__ W2Raw,
    const void* __restrict__ b2Raw, const int* __restrict__ flag,
    float* __restrict__ out) {
  __shared__ float sh[16 * 128];
  __shared__ float sqk[16 * 64];
  __shared__ float shw[16 * 15];
  __shared__ float sw[16 * 16];
  __shared__ float sagg[16 * 128];
  int bb = blockIdx.x, tid = threadIdx.x;
  const int f = *flag;

  for (int i = tid; i < 2048; i += 256) sh[i] = BF2F(h[(size_t)bb * 2048 + i]);
  for (int i = tid; i < 1024; i += 256) {
    int r = i >> 6, c = i & 63;
    sqk[i] = BF2F(G[(size_t)(bb * 16 + r) * gld + 1536 + c]);
  }
  for (int i = tid; i < 240; i += 256) shw[i] = hw[bb * 240 + i];
  __syncthreads();

  int a = tid >> 4, i = tid & 15;
  float s = -1e30f;
  if (i < 15) {
    int j = i + (i >= a);
    float d = 0.f;
    for (int c = 0; c < 32; ++c) d += sqk[a * 64 + c] * sqk[j * 64 + 32 + c];
    s = shw[a * 15 + i] * d * 0.17677669529663687f;  // *hard_w, /sqrt(32)
  }
  float mx = s;
#pragma unroll
  for (int d = 1; d < 16; d <<= 1) mx = fmaxf(mx, __shfl_xor(mx, d));
  float e = (i < 15) ? __expf(s - mx) : 0.f;
  float sum = e;
#pragma unroll
  for (int d = 1; d < 16; d <<= 1) sum += __shfl_xor(sum, d);
  float w = (i < 15) ? (e / sum) * shw[a * 15 + i] : 0.f;
  sw[a * 16 + i] = w;
  __syncthreads();

  float ac[8] = {0, 0, 0, 0, 0, 0, 0, 0};
  for (int mm = 0; mm < 15; ++mm) {
    int jm = mm + (mm >= a);
    float wm = sw[a * 16 + mm];
#pragma unroll
    for (int d = 0; d < 8; ++d) ac[d] += wm * sh[jm * 128 + i * 8 + d];
  }
#pragma unroll
  for (int d = 0; d < 8; ++d) sagg[a * 128 + i * 8 + d] = ac[d];
  __syncthreads();

  if (i < 14) {
    int o = i;
    float v = rdv(b2Raw, o, f);
    for (int c = 0; c < 128; ++c)
      v += sh[a * 128 + c] * rdv(W2Raw, o * 256 + c, f) +
           sagg[a * 128 + c] * rdv(W2Raw, o * 256 + 128 + c, f);
    out[(size_t)(bb * 16 + a) * 14 + o] = v;
  }
}

// ---------------------------------------------------------------------------
extern "C" void kernel_launch(void* const* d_in, const int* in_sizes, int n_in,
                              void* d_out, int out_size, void* d_ws, size_t ws_size,
                              hipStream_t stream) {
  // ---- ws layout (bytes); total 87,966,208 (proven available in round 2) ----
  const size_t OFF_ARENA = 0;          // 10,220,544 bf16 arena
  const size_t OFF_FLAG  = 10220544;   // 256
  const size_t OFF_A     = 10220800;   // 16,777,216 (x1+gi_c -> hp -> hw)
  const size_t OFF_WCAT  = 26998016;   // 409,600
  const size_t OFF_BCAT  = 27407616;   // 3,328
  const size_t OFF_HRNN  = 27410944;   // 4,194,304
  const size_t OFF_G     = 31605248;   // 52,428,800
  const size_t OFF_L     = 84034048;   // 3,932,160
  const size_t NEEDED    = 87966208;
  if (ws_size < NEEDED) return;  // signature: absmax == 1.1328 (zeros)
  // input-map sanity: mismatch -> zeros signature
  if (n_in < 23 || in_sizes[0] != 2097152 || in_sizes[3] != 16384 ||
      in_sizes[5] != 49152 || in_sizes[9] != 98304 || in_sizes[17] != 512 ||
      in_sizes[19] != 4096 || in_sizes[21] != 3584 || out_size != 2326528)
    return;

  char* ws = (char*)d_ws;
  bf*    arena = (bf*)(ws + OFF_ARENA);
  int*   flag  = (int*)(ws + OFF_FLAG);
  bf*    x1    = (bf*)(ws + OFF_A);
  bf*    gi_c  = (bf*)(ws + OFF_A + 4194304);
  bf*    hp    = (bf*)(ws + OFF_A);     // reuses x1+gi_c after cell
  float* hw    = (float*)(ws + OFF_A);  // reuses hp after steps
  bf*    Wcat  = (bf*)(ws + OFF_WCAT);
  bf*    bcat  = (bf*)(ws + OFF_BCAT);
  bf*    hrnn  = (bf*)(ws + OFF_HRNN);
  bf*    G     = (bf*)(ws + OFF_G);
  float* L     = (float*)(ws + OFF_L);

  float* out14 = (float*)d_out;
  float* outh  = (float*)d_out + 229376;  // h_rnn, fp32, 16384*128

  kDetect<<<1, 1024, 0, stream>>>((const unsigned short*)d_in[0], flag);
  CArgs ca;
  for (int i = 0; i < 23; ++i) { ca.src[i] = d_in[i]; ca.n[i] = AN[i]; ca.off[i] = AO[i]; }
  kConvert<<<dim3(128, 23), 256, 0, stream>>>(ca, flag, arena);

  const bf* inputs = arena + AO[0];
  const bf* hidden = arena + AO[1];
  const bf* W1     = arena + AO[3];
  const bf* b1     = arena + AO[4];
  const bf* Wih_c  = arena + AO[5];
  const bf* Whh_c  = arena + AO[6];
  const bf* bih_c  = arena + AO[7];
  const bf* bhh_c  = arena + AO[8];
  const bf* Wih_f  = arena + AO[9];
  const bf* Whh_f  = arena + AO[10];
  const bf* bih_f  = arena + AO[11];
  const bf* bhh_f  = arena + AO[12];
  const bf* Wih_b  = arena + AO[13];
  const bf* Whh_b  = arena + AO[14];
  const bf* bih_b  = arena + AO[15];
  const bf* bhh_b  = arena + AO[16];
  const bf* Wq     = arena + AO[19];
  const bf* Wk     = arena + AO[20];

  kPrep<<<dim3(800), 256, 0, stream>>>(Wih_f, bih_f, Wih_b, bih_b, Wq, Wk,
                                       Wcat, bcat);
  // x1 = relu(in @ W1^T + b1)
  kGemm<<<dim3(256, 2), 256, 0, stream>>>(inputs, W1, b1, x1, 128, 1);
  // gi_c = x1 @ Wih_c^T + bih_c
  kGemm<<<dim3(256, 6), 256, 0, stream>>>(x1, Wih_c, bih_c, gi_c, 384, 0);
  // h_rnn = GRUcell(x1, hidden); fp32 copy -> d_out h-section
  kStep<<<dim3(256, 1), 256, 0, stream>>>(
      hidden, (const bf*)nullptr, Whh_c, (const bf*)nullptr,
      gi_c, 384, 0, 0, /*has_nbr=*/0, 0, 0,
      bhh_c, (const bf*)nullptr, hrnn, (bf*)nullptr, outh,
      (const void*)nullptr, flag, (float*)nullptr);
  // G = h_rnn @ Wcat^T + bcat
  kGemm<<<dim3(256, 25), 256, 0, stream>>>(hrnn, Wcat, bcat, G, 1600, 0);

  for (int t = 0; t < 15; ++t) {
    bf* ho0 = hp + (size_t)(t & 1) * 2097152;
    bf* ho1 = hp + (size_t)(2 + (t & 1)) * 2097152;
    const bf* hp0 = t ? hp + (size_t)((t + 1) & 1) * 2097152 : (const bf*)nullptr;
    const bf* hp1 = t ? hp + (size_t)(2 + ((t + 1) & 1)) * 2097152 : (const bf*)nullptr;
    kStep<<<dim3(256, 2), 256, 0, stream>>>(
        hp0, hp1, Whh_f, Whh_b, G, 1600, /*goff*/ 0, 768,
        /*has_nbr=*/1, /*m0=*/t, /*m1=*/14 - t,
        bhh_f, bhh_b, ho0, ho1, (float*)nullptr,
        d_in[17], flag, L);
  }

  kGumbel<<<dim3(960), 256, 0, stream>>>(L, d_in[2], flag, d_in[18], hw);
  kAttn<<<dim3(1024), 256, 0, stream>>>(hrnn, G, 1600, hw, d_in[21], d_in[22],
                                        flag, out14);
}

// Round 5
// 849.298 us; speedup vs baseline: 1.2699x; 1.2699x over previous
//
#include <hip/hip_runtime.h>
#include <hip/hip_bf16.h>

// G2AAgent — ROUND 5: perf pass.
//  * kAttn: drop scalar projection (was 109us, VALUBusy 4.8%), write bf16 agg.
//  * kGemmOut: [h_rnn, agg] @ W2^T via MFMA (K=256 from two A sources).
//  * kStep: N-split by blockIdx.z (half=64 cols, acc 48 VGPR) -> 1024 blocks,
//    ~16 waves/CU (was 8). Logit partials go to 4 slots/row, kGumbel sums 8.
//  * L overlaps dead inputs/hidden arena; hw+agg overlap dead hp region.

typedef __attribute__((ext_vector_type(8))) short short8;
typedef __attribute__((ext_vector_type(4))) float float4v;

#define BF2F(x) __bfloat162float(x)
typedef __hip_bfloat16 bf;

__device__ __forceinline__ float fsigmoid(float x) {
  return 1.f / (1.f + __expf(-x));
}
__device__ __forceinline__ float ftanh(float x) {
  float ax = fabsf(x);
  float e = __expf(-2.f * ax);
  float t = (1.f - e) / (1.f + e);
  return x < 0.f ? -t : t;
}
__device__ __forceinline__ float rdv(const void* p, int i, int f) {
  return f ? ((const float*)p)[i] : BF2F(((const bf*)p)[i]);
}

// ---------------------------------------------------------------------------
static const int AO[23] = {
  0, 2097152, 4194304, 4685824, 4702208, 4702336, 4751488, 4800640, 4801024,
  4801408, 4899712, 4948864, 4949248, 4949632, 5047936, 5097088, 5097472,
  5097856, 5098368, 5098384, 5102480, 5106576, 5110160};
static const int AN[23] = {
  2097152, 2097152, 491520, 16384, 128, 49152, 49152, 384, 384, 98304, 49152,
  384, 384, 98304, 49152, 384, 384, 512, 2, 4096, 4096, 3584, 14};

struct CArgs {
  const void* src[23];
  int n[23];
  int off[23];
};

__global__ void kDetect(const unsigned short* __restrict__ p, int* flag) {
  __shared__ int s;
  if (threadIdx.x == 0) s = 0;
  __syncthreads();
  int hit = 0;
  for (int i = threadIdx.x; i < 4096; i += 1024) {
    int e = (p[i] >> 7) & 0xFF;
    if (e >= 0xC0) hit = 1;
  }
  if (hit) atomicOr(&s, 1);
  __syncthreads();
  if (threadIdx.x == 0) *flag = s;
}

__global__ void kConvert(CArgs a, const int* __restrict__ flag,
                         bf* __restrict__ arena) {
  const int b = blockIdx.y;
  const int n = a.n[b];
  const int f = *flag;
  bf* dst = arena + a.off[b];
  if (f) {
    const float* s = (const float*)a.src[b];
    for (int i = blockIdx.x * 256 + threadIdx.x; i < n; i += gridDim.x * 256)
      dst[i] = __float2bfloat16(s[i]);
  } else {
    const unsigned short* s = (const unsigned short*)a.src[b];
    unsigned short* d = (unsigned short*)dst;
    for (int i = blockIdx.x * 256 + threadIdx.x; i < n; i += gridDim.x * 256)
      d[i] = s[i];
  }
}

// ---------------------------------------------------------------------------
// kPrep: Wcat(1600x128), bcat(1600), W2p(16x256, rows 14/15 zero).
__global__ void kPrep(const bf* __restrict__ Wih_f, const bf* __restrict__ bih_f,
                      const bf* __restrict__ Wih_b, const bf* __restrict__ bih_b,
                      const bf* __restrict__ Wq, const bf* __restrict__ Wk,
                      const bf* __restrict__ W2a,
                      bf* __restrict__ Wcat, bf* __restrict__ bcat,
                      bf* __restrict__ W2p) {
  int idx = blockIdx.x * 256 + threadIdx.x;
  if (idx < 1600 * 128) {
    int r = idx >> 7, c = idx & 127;
    bf v;
    if (r < 384)       v = Wih_f[r * 256 + c];
    else if (r < 768)  v = Wih_f[(r - 384) * 256 + 128 + c];
    else if (r < 1152) v = Wih_b[(r - 768) * 256 + c];
    else if (r < 1536) v = Wih_b[(r - 1152) * 256 + 128 + c];
    else if (r < 1568) v = Wq[(r - 1536) * 128 + c];
    else               v = Wk[(r - 1568) * 128 + c];
    Wcat[idx] = v;
  }
  if (idx < 1600) {
    bf bv = __float2bfloat16(0.f);
    if (idx < 384) bv = bih_f[idx];
    else if (idx >= 768 && idx < 1152) bv = bih_b[idx - 768];
    bcat[idx] = bv;
  }
  if (idx < 4096)
    W2p[idx] = (idx < 3584) ? W2a[idx] : __float2bfloat16(0.f);
}

// ---------------------------------------------------------------------------
// kGemm: out[M x N](bf16) = A[M x 128] @ W[N x 128]^T + bias, optional relu.
__global__ __launch_bounds__(256) void kGemm(const bf* __restrict__ A,
                                             const bf* __restrict__ W,
                                             const bf* __restrict__ bias,
                                             bf* __restrict__ out,
                                             int N, int relu) {
  const int tid = threadIdx.x;
  const int wave = tid >> 6, lane = tid & 63;
  const int quad = lane >> 4, ci = lane & 15;
  const int mr = blockIdx.x * 64 + wave * 16;
  const int nbase = blockIdx.y * 64;

  float4v acc[4];
#pragma unroll
  for (int i = 0; i < 4; ++i) acc[i] = {0.f, 0.f, 0.f, 0.f};

#pragma unroll
  for (int ks = 0; ks < 4; ++ks) {
    short8 a = *(const short8*)(A + (size_t)(mr + ci) * 128 + ks * 32 + quad * 8);
#pragma unroll
    for (int nt = 0; nt < 4; ++nt) {
      short8 b = *(const short8*)(W + (size_t)(nbase + nt * 16 + ci) * 128 + ks * 32 + quad * 8);
      acc[nt] = __builtin_amdgcn_mfma_f32_16x16x32_bf16(a, b, acc[nt], 0, 0, 0);
    }
  }

#pragma unroll
  for (int nt = 0; nt < 4; ++nt) {
    int col = nbase + nt * 16 + ci;
    float bv = bias ? BF2F(bias[col]) : 0.f;
#pragma unroll
    for (int r = 0; r < 4; ++r) {
      int row = mr + quad * 4 + r;
      float v = acc[nt][r] + bv;
      if (relu) v = fmaxf(v, 0.f);
      out[(size_t)row * N + col] = __float2bfloat16(v);
    }
  }
}

// ---------------------------------------------------------------------------
// kStep: one GRU step; grid (256, ndir, 2). blockIdx.z = column half (64 cols).
// gh = Hp @ Whh^T (12 MFMA tiles); gi gathered from G; gates fused in epilogue.
// Logit partials -> L[row*120 + m*8 + dir*4 + half*2 + {0,1}].
__global__ __launch_bounds__(256, 4) void kStep(
    const bf* __restrict__ Hp0, const bf* __restrict__ Hp1,
    const bf* __restrict__ Whh0, const bf* __restrict__ Whh1,
    const bf* __restrict__ G, int gld, int goff0, int goff1,
    int has_nbr, int m0, int m1,
    const bf* __restrict__ bhh0, const bf* __restrict__ bhh1,
    bf* __restrict__ Ho0, bf* __restrict__ Ho1,
    float* __restrict__ HcopyF,
    const void* __restrict__ WcRaw, const int* __restrict__ flagp,
    float* __restrict__ L) {
  const int dir = blockIdx.y;
  const int half = blockIdx.z;
  const bf* Hp  = dir ? Hp1 : Hp0;
  const bf* Whh = dir ? Whh1 : Whh0;
  const bf* bhh = dir ? bhh1 : bhh0;
  bf* Ho        = dir ? Ho1 : Ho0;
  const int goff = dir ? goff1 : goff0;
  const int m    = dir ? m1 : m0;

  const int tid = threadIdx.x;
  const int wave = tid >> 6, lane = tid & 63;
  const int quad = lane >> 4, ci = lane & 15;
  const int mr = blockIdx.x * 64 + wave * 16;

  float4v acc[12];
#pragma unroll
  for (int i = 0; i < 12; ++i) acc[i] = {0.f, 0.f, 0.f, 0.f};

  if (Hp) {
#pragma unroll
    for (int ks = 0; ks < 4; ++ks) {
      short8 a = *(const short8*)(Hp + (size_t)(mr + ci) * 128 + ks * 32 + quad * 8);
#pragma unroll
      for (int g = 0; g < 3; ++g)
#pragma unroll
        for (int nt = 0; nt < 4; ++nt) {
          short8 b = *(const short8*)(Whh + (size_t)(g * 128 + half * 64 + nt * 16 + ci) * 128 + ks * 32 + quad * 8);
          acc[g * 4 + nt] = __builtin_amdgcn_mfma_f32_16x16x32_bf16(a, b, acc[g * 4 + nt], 0, 0, 0);
        }
    }
  }

  const int wf = flagp ? *flagp : 0;
  float bR[4], bZ[4], bN[4], wc0[4], wc1[4];
#pragma unroll
  for (int nt = 0; nt < 4; ++nt) {
    int c = half * 64 + nt * 16 + ci;
    bR[nt] = BF2F(bhh[c]);
    bZ[nt] = BF2F(bhh[128 + c]);
    bN[nt] = BF2F(bhh[256 + c]);
    if (WcRaw) {
      wc0[nt] = rdv(WcRaw, dir * 128 + c, wf);
      wc1[nt] = rdv(WcRaw, 256 + dir * 128 + c, wf);
    } else {
      wc0[nt] = 0.f; wc1[nt] = 0.f;
    }
  }

#pragma unroll
  for (int r = 0; r < 4; ++r) {
    int rr = mr + quad * 4 + r;
    const bf* gs = G + (size_t)rr * gld + goff;
    const bf* gn = nullptr;
    if (has_nbr) {
      int a_id = rr & 15;
      int j = m + (m >= a_id);
      gn = G + (size_t)((rr & ~15) | j) * gld + goff + 384;
    }
    float pl0 = 0.f, pl1 = 0.f;
#pragma unroll
    for (int nt = 0; nt < 4; ++nt) {
      int c = half * 64 + nt * 16 + ci;
      float gr = BF2F(gs[c]), gz = BF2F(gs[128 + c]), gnn = BF2F(gs[256 + c]);
      if (gn) {
        gr += BF2F(gn[c]); gz += BF2F(gn[128 + c]); gnn += BF2F(gn[256 + c]);
      }
      float pre_r = acc[nt][r] + gr + bR[nt];
      float pre_z = acc[4 + nt][r] + gz + bZ[nt];
      float hn_   = acc[8 + nt][r] + bN[nt];
      float rg = fsigmoid(pre_r);
      float zg = fsigmoid(pre_z);
      float ng = ftanh(gnn + rg * hn_);
      float hp = Hp ? BF2F(Hp[(size_t)rr * 128 + c]) : 0.f;
      float hv = (1.f - zg) * ng + zg * hp;
      Ho[(size_t)rr * 128 + c] = __float2bfloat16(hv);
      if (HcopyF) HcopyF[(size_t)rr * 128 + c] = hv;
      pl0 += hv * wc0[nt];
      pl1 += hv * wc1[nt];
    }
    if (WcRaw) {
#pragma unroll
      for (int d = 1; d < 16; d <<= 1) {
        pl0 += __shfl_xor(pl0, d);
        pl1 += __shfl_xor(pl1, d);
      }
      if (ci == 0) {
        float* Lp = L + (size_t)rr * 120 + m * 8 + dir * 4 + half * 2;
        Lp[0] = pl0;
        Lp[1] = pl1;
      }
    }
  }
}

// ---------------------------------------------------------------------------
// kGumbel: hard_w = sigmoid(((l1+g1)-(l0+g0)) / TAU), TAU=0.5. Sums 4 partial
// slots per logit (dir x half).
__global__ void kGumbel(const float* __restrict__ L, const void* __restrict__ guRaw,
                        const int* __restrict__ flag, const void* __restrict__ bcRaw,
                        float* __restrict__ hw) {
  int idx = blockIdx.x * 256 + threadIdx.x;
  if (idx >= 245760) return;
  const int f = *flag;
  int row = idx / 15, mm = idx - row * 15;
  const float* Lp = L + (size_t)row * 120 + mm * 8;
  float l0 = Lp[0] + Lp[2] + Lp[4] + Lp[6] + rdv(bcRaw, 0, f);
  float l1 = Lp[1] + Lp[3] + Lp[5] + Lp[7] + rdv(bcRaw, 1, f);
  float u0 = rdv(guRaw, idx * 2, f);
  float u1 = rdv(guRaw, idx * 2 + 1, f);
  float g0 = -__logf(-__logf(u0 + 1e-10f) + 1e-10f);
  float g1 = -__logf(-__logf(u1 + 1e-10f) + 1e-10f);
  float d = ((l1 + g1) - (l0 + g0)) * 2.0f;
  hw[idx] = fsigmoid(d);
}

// ---------------------------------------------------------------------------
// kAttn: per-env attention; writes agg (bf16, 16384x128). No projection here.
__global__ __launch_bounds__(256) void kAttn(
    const bf* __restrict__ h, const bf* __restrict__ G, int gld,
    const float* __restrict__ hw, bf* __restrict__ aggB) {
  __shared__ float sh[16 * 132];   // padded stride vs bank conflicts
  __shared__ float sqk[16 * 64];
  __shared__ float shw[16 * 15];
  __shared__ float sw[16 * 16];
  int bb = blockIdx.x, tid = threadIdx.x;

  for (int i = tid; i < 2048; i += 256)
    sh[(i >> 7) * 132 + (i & 127)] = BF2F(h[(size_t)bb * 2048 + i]);
  for (int i = tid; i < 1024; i += 256) {
    int r = i >> 6, c = i & 63;
    sqk[i] = BF2F(G[(size_t)(bb * 16 + r) * gld + 1536 + c]);
  }
  for (int i = tid; i < 240; i += 256) shw[i] = hw[bb * 240 + i];
  __syncthreads();

  int a = tid >> 4, i = tid & 15;
  float s = -1e30f;
  if (i < 15) {
    int j = i + (i >= a);
    float d = 0.f;
#pragma unroll
    for (int c = 0; c < 32; ++c) d += sqk[a * 64 + c] * sqk[j * 64 + 32 + c];
    s = shw[a * 15 + i] * d * 0.17677669529663687f;  // *hard_w, /sqrt(32)
  }
  float mx = s;
#pragma unroll
  for (int d = 1; d < 16; d <<= 1) mx = fmaxf(mx, __shfl_xor(mx, d));
  float e = (i < 15) ? __expf(s - mx) : 0.f;
  float sum = e;
#pragma unroll
  for (int d = 1; d < 16; d <<= 1) sum += __shfl_xor(sum, d);
  float w = (i < 15) ? (e / sum) * shw[a * 15 + i] : 0.f;
  sw[a * 16 + i] = w;
  __syncthreads();

  float ac[8] = {0, 0, 0, 0, 0, 0, 0, 0};
  for (int mm = 0; mm < 15; ++mm) {
    int jm = mm + (mm >= a);
    float wm = sw[a * 16 + mm];
    const float* shp = &sh[jm * 132 + i * 8];
    float4 h0 = *(const float4*)shp;
    float4 h1 = *(const float4*)(shp + 4);
    ac[0] += wm * h0.x; ac[1] += wm * h0.y; ac[2] += wm * h0.z; ac[3] += wm * h0.w;
    ac[4] += wm * h1.x; ac[5] += wm * h1.y; ac[6] += wm * h1.z; ac[7] += wm * h1.w;
  }
  short8 v;
#pragma unroll
  for (int d = 0; d < 8; ++d) {
    bf b = __float2bfloat16(ac[d]);
    v[d] = *(short*)&b;
  }
  *(short8*)(aggB + (size_t)(bb * 16 + a) * 128 + i * 8) = v;
}

// ---------------------------------------------------------------------------
// kGemmOut: out14[16384 x 14] (fp32) = [h_rnn, agg] @ W2p^T + b2.
// K=256: ks 0..3 A from hrnn, ks 4..7 A from aggB. N=16 padded (rows 14/15=0).
__global__ __launch_bounds__(256) void kGemmOut(
    const bf* __restrict__ hrnn, const bf* __restrict__ aggB,
    const bf* __restrict__ W2p, const void* __restrict__ b2Raw,
    const int* __restrict__ flag, float* __restrict__ out) {
  const int tid = threadIdx.x;
  const int wave = tid >> 6, lane = tid & 63;
  const int quad = lane >> 4, ci = lane & 15;
  const int mr = blockIdx.x * 64 + wave * 16;
  const int f = *flag;

  float4v acc = {0.f, 0.f, 0.f, 0.f};
#pragma unroll
  for (int ks = 0; ks < 8; ++ks) {
    const bf* src = (ks < 4) ? hrnn : aggB;
    int k = (ks & 3) * 32 + quad * 8;
    short8 a = *(const short8*)(src + (size_t)(mr + ci) * 128 + k);
    short8 b = *(const short8*)(W2p + (size_t)ci * 256 + ks * 32 + quad * 8);
    acc = __builtin_amdgcn_mfma_f32_16x16x32_bf16(a, b, acc, 0, 0, 0);
  }

  if (ci < 14) {
    float bv = rdv(b2Raw, ci, f);
#pragma unroll
    for (int r = 0; r < 4; ++r)
      out[(size_t)(mr + quad * 4 + r) * 14 + ci] = acc[r] + bv;
  }
}

// ---------------------------------------------------------------------------
extern "C" void kernel_launch(void* const* d_in, const int* in_sizes, int n_in,
                              void* d_out, int out_size, void* d_ws, size_t ws_size,
                              hipStream_t stream) {
  // ---- ws layout (bytes); NEEDED = 84,042,240 < 87,966,208 (proven) ----
  const size_t OFF_ARENA = 0;          // 10,220,544 bf16 arena; L overlaps
                                       //   bytes [0, 7,864,320) after cell
  const size_t OFF_FLAG  = 10220544;   // 256
  const size_t OFF_A     = 10220800;   // 16,777,216: x1+gi_c -> hp -> hw+agg
  const size_t OFF_WCAT  = 26998016;   // 409,600
  const size_t OFF_BCAT  = 27407616;   // 3,328
  const size_t OFF_W2P   = 27410944;   // 8,192
  const size_t OFF_HRNN  = 27419136;   // 4,194,304
  const size_t OFF_G     = 31613440;   // 52,428,800 (end 84,042,240)
  const size_t NEEDED    = 84042240;
  if (ws_size < NEEDED) return;
  if (n_in < 23 || in_sizes[0] != 2097152 || in_sizes[3] != 16384 ||
      in_sizes[5] != 49152 || in_sizes[9] != 98304 || in_sizes[17] != 512 ||
      in_sizes[19] != 4096 || in_sizes[21] != 3584 || out_size != 2326528)
    return;

  char* ws = (char*)d_ws;
  bf*    arena = (bf*)(ws + OFF_ARENA);
  float* L     = (float*)(ws + OFF_ARENA);          // 7,864,320 B, after cell
  int*   flag  = (int*)(ws + OFF_FLAG);
  bf*    x1    = (bf*)(ws + OFF_A);
  bf*    gi_c  = (bf*)(ws + OFF_A + 4194304);
  bf*    hp    = (bf*)(ws + OFF_A);                 // reuses x1+gi_c
  float* hw    = (float*)(ws + OFF_A);              // reuses hp (983,040 B)
  bf*    aggB  = (bf*)(ws + OFF_A + 983040);        // 4,194,304 B
  bf*    Wcat  = (bf*)(ws + OFF_WCAT);
  bf*    bcat  = (bf*)(ws + OFF_BCAT);
  bf*    W2p   = (bf*)(ws + OFF_W2P);
  bf*    hrnn  = (bf*)(ws + OFF_HRNN);
  bf*    G     = (bf*)(ws + OFF_G);

  float* out14 = (float*)d_out;
  float* outh  = (float*)d_out + 229376;  // h_rnn fp32, 16384*128

  kDetect<<<1, 1024, 0, stream>>>((const unsigned short*)d_in[0], flag);
  CArgs ca;
  for (int i = 0; i < 23; ++i) { ca.src[i] = d_in[i]; ca.n[i] = AN[i]; ca.off[i] = AO[i]; }
  kConvert<<<dim3(128, 23), 256, 0, stream>>>(ca, flag, arena);

  const bf* inputs = arena + AO[0];
  const bf* hidden = arena + AO[1];
  const bf* W1     = arena + AO[3];
  const bf* b1     = arena + AO[4];
  const bf* Wih_c  = arena + AO[5];
  const bf* Whh_c  = arena + AO[6];
  const bf* bih_c  = arena + AO[7];
  const bf* bhh_c  = arena + AO[8];
  const bf* Wih_f  = arena + AO[9];
  const bf* Whh_f  = arena + AO[10];
  const bf* bih_f  = arena + AO[11];
  const bf* bhh_f  = arena + AO[12];
  const bf* Wih_b  = arena + AO[13];
  const bf* Whh_b  = arena + AO[14];
  const bf* bih_b  = arena + AO[15];
  const bf* bhh_b  = arena + AO[16];
  const bf* Wq     = arena + AO[19];
  const bf* Wk     = arena + AO[20];
  const bf* W2a    = arena + AO[21];

  kPrep<<<dim3(800), 256, 0, stream>>>(Wih_f, bih_f, Wih_b, bih_b, Wq, Wk, W2a,
                                       Wcat, bcat, W2p);
  kGemm<<<dim3(256, 2), 256, 0, stream>>>(inputs, W1, b1, x1, 128, 1);
  kGemm<<<dim3(256, 6), 256, 0, stream>>>(x1, Wih_c, bih_c, gi_c, 384, 0);
  // cell GRU: h_rnn (bf16 + fp32 copy to d_out)
  kStep<<<dim3(256, 1, 2), 256, 0, stream>>>(
      hidden, (const bf*)nullptr, Whh_c, (const bf*)nullptr,
      gi_c, 384, 0, 0, /*has_nbr=*/0, 0, 0,
      bhh_c, (const bf*)nullptr, hrnn, (bf*)nullptr, outh,
      (const void*)nullptr, flag, (float*)nullptr);
  kGemm<<<dim3(256, 25), 256, 0, stream>>>(hrnn, Wcat, bcat, G, 1600, 0);

  for (int t = 0; t < 15; ++t) {
    bf* ho0 = hp + (size_t)(t & 1) * 2097152;
    bf* ho1 = hp + (size_t)(2 + (t & 1)) * 2097152;
    const bf* hp0 = t ? hp + (size_t)((t + 1) & 1) * 2097152 : (const bf*)nullptr;
    const bf* hp1 = t ? hp + (size_t)(2 + ((t + 1) & 1)) * 2097152 : (const bf*)nullptr;
    kStep<<<dim3(256, 2, 2), 256, 0, stream>>>(
        hp0, hp1, Whh_f, Whh_b, G, 1600, /*goff*/ 0, 768,
        /*has_nbr=*/1, /*m0=*/t, /*m1=*/14 - t,
        bhh_f, bhh_b, ho0, ho1, (float*)nullptr,
        d_in[17], flag, L);
  }

  kGumbel<<<dim3(960), 256, 0, stream>>>(L, d_in[2], flag, d_in[18], hw);
  kAttn<<<dim3(1024), 256, 0, stream>>>(hrnn, G, 1600, hw, aggB);
  kGemmOut<<<dim3(256), 256, 0, stream>>>(hrnn, aggB, W2p, d_in[22], flag, out14);
}

// Round 6
// 780.811 us; speedup vs baseline: 1.3813x; 1.0877x over previous
//
#include <hip/hip_runtime.h>
#include <hip/hip_bf16.h>

// G2AAgent — ROUND 6: fuse the 15-step bidirectional GRU into ONE kernel.
// Insight: yf/yb only feed logits (L); all cross-row coupling is within an
// env (nbr rows {m, m+1} of the same 16-agent group). So one block per env
// runs all 15 steps with h ping-pong + self-G staged in LDS. Removes 15
// launches, 15x Hp HBM reads, 15x h HBM writes, and all scalar G gathers.

typedef __attribute__((ext_vector_type(8))) short short8;
typedef __attribute__((ext_vector_type(4))) float float4v;

#define BF2F(x) __bfloat162float(x)
typedef __hip_bfloat16 bf;

__device__ __forceinline__ float fsigmoid(float x) {
  return 1.f / (1.f + __expf(-x));
}
__device__ __forceinline__ float ftanh(float x) {
  float ax = fabsf(x);
  float e = __expf(-2.f * ax);
  float t = (1.f - e) / (1.f + e);
  return x < 0.f ? -t : t;
}
__device__ __forceinline__ float rdv(const void* p, int i, int f) {
  return f ? ((const float*)p)[i] : BF2F(((const bf*)p)[i]);
}

// ---------------------------------------------------------------------------
static const int AO[23] = {
  0, 2097152, 4194304, 4685824, 4702208, 4702336, 4751488, 4800640, 4801024,
  4801408, 4899712, 4948864, 4949248, 4949632, 5047936, 5097088, 5097472,
  5097856, 5098368, 5098384, 5102480, 5106576, 5110160};
static const int AN[23] = {
  2097152, 2097152, 491520, 16384, 128, 49152, 49152, 384, 384, 98304, 49152,
  384, 384, 98304, 49152, 384, 384, 512, 2, 4096, 4096, 3584, 14};

struct CArgs {
  const void* src[23];
  int n[23];
  int off[23];
};

__global__ void kDetect(const unsigned short* __restrict__ p, int* flag) {
  __shared__ int s;
  if (threadIdx.x == 0) s = 0;
  __syncthreads();
  int hit = 0;
  for (int i = threadIdx.x; i < 4096; i += 1024) {
    int e = (p[i] >> 7) & 0xFF;
    if (e >= 0xC0) hit = 1;
  }
  if (hit) atomicOr(&s, 1);
  __syncthreads();
  if (threadIdx.x == 0) *flag = s;
}

__global__ void kConvert(CArgs a, const int* __restrict__ flag,
                         bf* __restrict__ arena) {
  const int b = blockIdx.y;
  const int n = a.n[b];
  const int f = *flag;
  bf* dst = arena + a.off[b];
  if (f) {
    const float* s = (const float*)a.src[b];
    for (int i = blockIdx.x * 256 + threadIdx.x; i < n; i += gridDim.x * 256)
      dst[i] = __float2bfloat16(s[i]);
  } else {
    const unsigned short* s = (const unsigned short*)a.src[b];
    unsigned short* d = (unsigned short*)dst;
    for (int i = blockIdx.x * 256 + threadIdx.x; i < n; i += gridDim.x * 256)
      d[i] = s[i];
  }
}

// ---------------------------------------------------------------------------
// kPrep: Wcat(1600x128), bcat(1600), W2p(16x256, rows 14/15 zero).
__global__ void kPrep(const bf* __restrict__ Wih_f, const bf* __restrict__ bih_f,
                      const bf* __restrict__ Wih_b, const bf* __restrict__ bih_b,
                      const bf* __restrict__ Wq, const bf* __restrict__ Wk,
                      const bf* __restrict__ W2a,
                      bf* __restrict__ Wcat, bf* __restrict__ bcat,
                      bf* __restrict__ W2p) {
  int idx = blockIdx.x * 256 + threadIdx.x;
  if (idx < 1600 * 128) {
    int r = idx >> 7, c = idx & 127;
    bf v;
    if (r < 384)       v = Wih_f[r * 256 + c];
    else if (r < 768)  v = Wih_f[(r - 384) * 256 + 128 + c];
    else if (r < 1152) v = Wih_b[(r - 768) * 256 + c];
    else if (r < 1536) v = Wih_b[(r - 1152) * 256 + 128 + c];
    else if (r < 1568) v = Wq[(r - 1536) * 128 + c];
    else               v = Wk[(r - 1568) * 128 + c];
    Wcat[idx] = v;
  }
  if (idx < 1600) {
    bf bv = __float2bfloat16(0.f);
    if (idx < 384) bv = bih_f[idx];
    else if (idx >= 768 && idx < 1152) bv = bih_b[idx - 768];
    bcat[idx] = bv;
  }
  if (idx < 4096)
    W2p[idx] = (idx < 3584) ? W2a[idx] : __float2bfloat16(0.f);
}

// ---------------------------------------------------------------------------
// kGemm: out[M x N](bf16) = A[M x 128] @ W[N x 128]^T + bias, optional relu.
__global__ __launch_bounds__(256) void kGemm(const bf* __restrict__ A,
                                             const bf* __restrict__ W,
                                             const bf* __restrict__ bias,
                                             bf* __restrict__ out,
                                             int N, int relu) {
  const int tid = threadIdx.x;
  const int wave = tid >> 6, lane = tid & 63;
  const int quad = lane >> 4, ci = lane & 15;
  const int mr = blockIdx.x * 64 + wave * 16;
  const int nbase = blockIdx.y * 64;

  float4v acc[4];
#pragma unroll
  for (int i = 0; i < 4; ++i) acc[i] = {0.f, 0.f, 0.f, 0.f};

#pragma unroll
  for (int ks = 0; ks < 4; ++ks) {
    short8 a = *(const short8*)(A + (size_t)(mr + ci) * 128 + ks * 32 + quad * 8);
#pragma unroll
    for (int nt = 0; nt < 4; ++nt) {
      short8 b = *(const short8*)(W + (size_t)(nbase + nt * 16 + ci) * 128 + ks * 32 + quad * 8);
      acc[nt] = __builtin_amdgcn_mfma_f32_16x16x32_bf16(a, b, acc[nt], 0, 0, 0);
    }
  }

#pragma unroll
  for (int nt = 0; nt < 4; ++nt) {
    int col = nbase + nt * 16 + ci;
    float bv = bias ? BF2F(bias[col]) : 0.f;
#pragma unroll
    for (int r = 0; r < 4; ++r) {
      int row = mr + quad * 4 + r;
      float v = acc[nt][r] + bv;
      if (relu) v = fmaxf(v, 0.f);
      out[(size_t)row * N + col] = __float2bfloat16(v);
    }
  }
}

// ---------------------------------------------------------------------------
// kStep: single GRU step (used only for the "cell" GRU now).
__global__ __launch_bounds__(256, 4) void kStep(
    const bf* __restrict__ Hp0, const bf* __restrict__ Whh0,
    const bf* __restrict__ G, int gld,
    const bf* __restrict__ bhh0,
    bf* __restrict__ Ho0, float* __restrict__ HcopyF) {
  const int half = blockIdx.z;
  const bf* Hp  = Hp0;
  const bf* Whh = Whh0;
  const bf* bhh = bhh0;
  bf* Ho        = Ho0;

  const int tid = threadIdx.x;
  const int wave = tid >> 6, lane = tid & 63;
  const int quad = lane >> 4, ci = lane & 15;
  const int mr = blockIdx.x * 64 + wave * 16;

  float4v acc[12];
#pragma unroll
  for (int i = 0; i < 12; ++i) acc[i] = {0.f, 0.f, 0.f, 0.f};

#pragma unroll
  for (int ks = 0; ks < 4; ++ks) {
    short8 a = *(const short8*)(Hp + (size_t)(mr + ci) * 128 + ks * 32 + quad * 8);
#pragma unroll
    for (int g = 0; g < 3; ++g)
#pragma unroll
      for (int nt = 0; nt < 4; ++nt) {
        short8 b = *(const short8*)(Whh + (size_t)(g * 128 + half * 64 + nt * 16 + ci) * 128 + ks * 32 + quad * 8);
        acc[g * 4 + nt] = __builtin_amdgcn_mfma_f32_16x16x32_bf16(a, b, acc[g * 4 + nt], 0, 0, 0);
      }
  }

  float bR[4], bZ[4], bN[4];
#pragma unroll
  for (int nt = 0; nt < 4; ++nt) {
    int c = half * 64 + nt * 16 + ci;
    bR[nt] = BF2F(bhh[c]);
    bZ[nt] = BF2F(bhh[128 + c]);
    bN[nt] = BF2F(bhh[256 + c]);
  }

#pragma unroll
  for (int r = 0; r < 4; ++r) {
    int rr = mr + quad * 4 + r;
    const bf* gs = G + (size_t)rr * gld;
#pragma unroll
    for (int nt = 0; nt < 4; ++nt) {
      int c = half * 64 + nt * 16 + ci;
      float gr = BF2F(gs[c]), gz = BF2F(gs[128 + c]), gnn = BF2F(gs[256 + c]);
      float pre_r = acc[nt][r] + gr + bR[nt];
      float pre_z = acc[4 + nt][r] + gz + bZ[nt];
      float hn_   = acc[8 + nt][r] + bN[nt];
      float rg = fsigmoid(pre_r);
      float zg = fsigmoid(pre_z);
      float ng = ftanh(gnn + rg * hn_);
      float hp = BF2F(Hp[(size_t)rr * 128 + c]);
      float hv = (1.f - zg) * ng + zg * hp;
      Ho[(size_t)rr * 128 + c] = __float2bfloat16(hv);
      if (HcopyF) HcopyF[(size_t)rr * 128 + c] = hv;
    }
  }
}

// ---------------------------------------------------------------------------
// kSeq: the fused 15-step bidirectional GRU. grid 1024 (1 env/block), 256 thr
// = 4 waves: wave = dir*? -> dir = wave&1, nhalf = wave>>1. Self-G staged in
// LDS once; nbr rows {m, m+1} staged per step; h ping-pong in LDS (stride 136
// -> 2-way bank aliasing, free). Logit partials -> L.
__global__ __launch_bounds__(256, 3) void kSeq(
    const bf* __restrict__ G,
    const bf* __restrict__ Whh_f, const bf* __restrict__ Whh_b,
    const bf* __restrict__ bhh_f, const bf* __restrict__ bhh_b,
    const void* __restrict__ WcRaw, const int* __restrict__ flagp,
    float* __restrict__ L) {
  __shared__ bf sG[2][16][384];      // self gi: [dir][row][gate*128+c]  24 KB
  __shared__ bf sN[2][2][384];       // nbr gi rows {m,m+1}: [dir][jj][..] 3 KB
  __shared__ bf sH[2][2][16][136];   // h ping-pong: [buf][dir][row][c]  17 KB

  const int env = blockIdx.x;
  const int tid = threadIdx.x;
  const int wave = tid >> 6, lane = tid & 63;
  const int dir = wave & 1, nh = wave >> 1;
  const int quad = lane >> 4, ci = lane & 15;
  const bf* Whh = dir ? Whh_b : Whh_f;
  const bf* bhh = dir ? bhh_b : bhh_f;
  const int f = *flagp;

  // stage self-G (both dir regions: f cols 0..384, b cols 768..1152)
  for (int i = tid; i < 1536; i += 256) {
    int d = i >= 768;
    int idx = i & 767;
    int row = idx / 48, ch = idx - row * 48;
    *(short8*)&sG[d][row][ch * 8] =
        *(const short8*)(G + (size_t)(env * 16 + row) * 1600 + d * 768 + ch * 8);
  }
  // zero h buffer 0
  {
    bf z = __float2bfloat16(0.f);
    bf* p = &sH[0][0][0][0];
    for (int i = tid; i < 2 * 16 * 136; i += 256) p[i] = z;
  }

  // per-thread column constants (c = nh*64 + nt*16 + ci)
  float bR[4], bZ[4], bN[4], wc0[4], wc1[4];
#pragma unroll
  for (int nt = 0; nt < 4; ++nt) {
    int c = nh * 64 + nt * 16 + ci;
    bR[nt] = BF2F(bhh[c]);
    bZ[nt] = BF2F(bhh[128 + c]);
    bN[nt] = BF2F(bhh[256 + c]);
    wc0[nt] = rdv(WcRaw, dir * 128 + c, f);
    wc1[nt] = rdv(WcRaw, 256 + dir * 128 + c, f);
  }
  __syncthreads();

  for (int t = 0; t < 15; ++t) {
    const int cur = t & 1, nxt = cur ^ 1;
    const int m = dir ? (14 - t) : t;

    // stage nbr rows {m_d, m_d+1} for both dirs (192 short8 chunks)
    if (tid < 192) {
      int d = tid / 96;
      int r2 = (tid - d * 96) / 48;     // 0 or 1
      int ch = tid % 48;
      int md = d ? (14 - t) : t;
      *(short8*)&sN[d][r2][ch * 8] =
          *(const short8*)(G + (size_t)(env * 16 + md + r2) * 1600 + d * 768 + 384 + ch * 8);
    }

    // gh = h @ Whh^T for this wave's (dir, nhalf): 12 tiles M=16 N=16 K=128
    float4v acc[12];
#pragma unroll
    for (int i = 0; i < 12; ++i) acc[i] = {0.f, 0.f, 0.f, 0.f};
#pragma unroll
    for (int ks = 0; ks < 4; ++ks) {
      short8 a = *(const short8*)&sH[cur][dir][ci][ks * 32 + quad * 8];
#pragma unroll
      for (int tl = 0; tl < 12; ++tl) {
        int rowb = (tl >> 2) * 128 + nh * 64 + (tl & 3) * 16 + ci;
        short8 b = *(const short8*)(Whh + (size_t)rowb * 128 + ks * 32 + quad * 8);
        acc[tl] = __builtin_amdgcn_mfma_f32_16x16x32_bf16(a, b, acc[tl], 0, 0, 0);
      }
    }
    __syncthreads();  // sN staged; all waves done reading sH[cur] as A-frags

#pragma unroll
    for (int r_ = 0; r_ < 4; ++r_) {
      int row = quad * 4 + r_;           // local agent id a
      int jj = (m >= row) ? 1 : 0;       // nbr j = m + jj
      float pl0 = 0.f, pl1 = 0.f;
#pragma unroll
      for (int nt = 0; nt < 4; ++nt) {
        int c = nh * 64 + nt * 16 + ci;
        float gr  = BF2F(sG[dir][row][c])       + BF2F(sN[dir][jj][c]);
        float gz  = BF2F(sG[dir][row][128 + c]) + BF2F(sN[dir][jj][128 + c]);
        float gnn = BF2F(sG[dir][row][256 + c]) + BF2F(sN[dir][jj][256 + c]);
        float pre_r = acc[nt][r_] + gr + bR[nt];
        float pre_z = acc[4 + nt][r_] + gz + bZ[nt];
        float hn_   = acc[8 + nt][r_] + bN[nt];
        float rg = fsigmoid(pre_r);
        float zg = fsigmoid(pre_z);
        float ng = ftanh(gnn + rg * hn_);
        float hp = BF2F(sH[cur][dir][row][c]);
        float hv = (1.f - zg) * ng + zg * hp;
        sH[nxt][dir][row][c] = __float2bfloat16(hv);
        pl0 += hv * wc0[nt];
        pl1 += hv * wc1[nt];
      }
#pragma unroll
      for (int d = 1; d < 16; d <<= 1) {
        pl0 += __shfl_xor(pl0, d);
        pl1 += __shfl_xor(pl1, d);
      }
      if (ci == 0) {
        float* Lp = L + (size_t)(env * 16 + row) * 120 + m * 8 + dir * 4 + nh * 2;
        Lp[0] = pl0;
        Lp[1] = pl1;
      }
    }
    __syncthreads();  // sH[nxt] complete; sN free for next stage
  }
}

// ---------------------------------------------------------------------------
// kGumbel: hard_w = sigmoid(((l1+g1)-(l0+g0)) / TAU), TAU=0.5. Sums 4 partial
// slots per logit (dir x half).
__global__ void kGumbel(const float* __restrict__ L, const void* __restrict__ guRaw,
                        const int* __restrict__ flag, const void* __restrict__ bcRaw,
                        float* __restrict__ hw) {
  int idx = blockIdx.x * 256 + threadIdx.x;
  if (idx >= 245760) return;
  const int f = *flag;
  int row = idx / 15, mm = idx - row * 15;
  const float* Lp = L + (size_t)row * 120 + mm * 8;
  float l0 = Lp[0] + Lp[2] + Lp[4] + Lp[6] + rdv(bcRaw, 0, f);
  float l1 = Lp[1] + Lp[3] + Lp[5] + Lp[7] + rdv(bcRaw, 1, f);
  float u0 = rdv(guRaw, idx * 2, f);
  float u1 = rdv(guRaw, idx * 2 + 1, f);
  float g0 = -__logf(-__logf(u0 + 1e-10f) + 1e-10f);
  float g1 = -__logf(-__logf(u1 + 1e-10f) + 1e-10f);
  float d = ((l1 + g1) - (l0 + g0)) * 2.0f;
  hw[idx] = fsigmoid(d);
}

// ---------------------------------------------------------------------------
// kAttn: per-env attention; writes agg (bf16, 16384x128).
__global__ __launch_bounds__(256) void kAttn(
    const bf* __restrict__ h, const bf* __restrict__ G, int gld,
    const float* __restrict__ hw, bf* __restrict__ aggB) {
  __shared__ float sh[16 * 132];
  __shared__ float sqk[16 * 64];
  __shared__ float shw[16 * 15];
  __shared__ float sw[16 * 16];
  int bb = blockIdx.x, tid = threadIdx.x;

  for (int i = tid; i < 2048; i += 256)
    sh[(i >> 7) * 132 + (i & 127)] = BF2F(h[(size_t)bb * 2048 + i]);
  for (int i = tid; i < 1024; i += 256) {
    int r = i >> 6, c = i & 63;
    sqk[i] = BF2F(G[(size_t)(bb * 16 + r) * gld + 1536 + c]);
  }
  for (int i = tid; i < 240; i += 256) shw[i] = hw[bb * 240 + i];
  __syncthreads();

  int a = tid >> 4, i = tid & 15;
  float s = -1e30f;
  if (i < 15) {
    int j = i + (i >= a);
    float d = 0.f;
#pragma unroll
    for (int c = 0; c < 32; ++c) d += sqk[a * 64 + c] * sqk[j * 64 + 32 + c];
    s = shw[a * 15 + i] * d * 0.17677669529663687f;
  }
  float mx = s;
#pragma unroll
  for (int d = 1; d < 16; d <<= 1) mx = fmaxf(mx, __shfl_xor(mx, d));
  float e = (i < 15) ? __expf(s - mx) : 0.f;
  float sum = e;
#pragma unroll
  for (int d = 1; d < 16; d <<= 1) sum += __shfl_xor(sum, d);
  float w = (i < 15) ? (e / sum) * shw[a * 15 + i] : 0.f;
  sw[a * 16 + i] = w;
  __syncthreads();

  float ac[8] = {0, 0, 0, 0, 0, 0, 0, 0};
  for (int mm = 0; mm < 15; ++mm) {
    int jm = mm + (mm >= a);
    float wm = sw[a * 16 + mm];
    const float* shp = &sh[jm * 132 + i * 8];
    float4 h0 = *(const float4*)shp;
    float4 h1 = *(const float4*)(shp + 4);
    ac[0] += wm * h0.x; ac[1] += wm * h0.y; ac[2] += wm * h0.z; ac[3] += wm * h0.w;
    ac[4] += wm * h1.x; ac[5] += wm * h1.y; ac[6] += wm * h1.z; ac[7] += wm * h1.w;
  }
  short8 v;
#pragma unroll
  for (int d = 0; d < 8; ++d) {
    bf b = __float2bfloat16(ac[d]);
    v[d] = *(short*)&b;
  }
  *(short8*)(aggB + (size_t)(bb * 16 + a) * 128 + i * 8) = v;
}

// ---------------------------------------------------------------------------
// kGemmOut: out14[16384 x 14] (fp32) = [h_rnn, agg] @ W2p^T + b2.
__global__ __launch_bounds__(256) void kGemmOut(
    const bf* __restrict__ hrnn, const bf* __restrict__ aggB,
    const bf* __restrict__ W2p, const void* __restrict__ b2Raw,
    const int* __restrict__ flag, float* __restrict__ out) {
  const int tid = threadIdx.x;
  const int wave = tid >> 6, lane = tid & 63;
  const int quad = lane >> 4, ci = lane & 15;
  const int mr = blockIdx.x * 64 + wave * 16;
  const int f = *flag;

  float4v acc = {0.f, 0.f, 0.f, 0.f};
#pragma unroll
  for (int ks = 0; ks < 8; ++ks) {
    const bf* src = (ks < 4) ? hrnn : aggB;
    int k = (ks & 3) * 32 + quad * 8;
    short8 a = *(const short8*)(src + (size_t)(mr + ci) * 128 + k);
    short8 b = *(const short8*)(W2p + (size_t)ci * 256 + ks * 32 + quad * 8);
    acc = __builtin_amdgcn_mfma_f32_16x16x32_bf16(a, b, acc, 0, 0, 0);
  }

  if (ci < 14) {
    float bv = rdv(b2Raw, ci, f);
#pragma unroll
    for (int r = 0; r < 4; ++r)
      out[(size_t)(mr + quad * 4 + r) * 14 + ci] = acc[r] + bv;
  }
}

// ---------------------------------------------------------------------------
extern "C" void kernel_launch(void* const* d_in, const int* in_sizes, int n_in,
                              void* d_out, int out_size, void* d_ws, size_t ws_size,
                              hipStream_t stream) {
  const size_t OFF_ARENA = 0;          // bf16 arena; L overlaps [0, 7.86MB) later
  const size_t OFF_FLAG  = 10220544;
  const size_t OFF_A     = 10220800;   // x1+gi_c -> hw+agg
  const size_t OFF_WCAT  = 26998016;
  const size_t OFF_BCAT  = 27407616;
  const size_t OFF_W2P   = 27410944;
  const size_t OFF_HRNN  = 27419136;
  const size_t OFF_G     = 31613440;   // 52,428,800 (end 84,042,240)
  const size_t NEEDED    = 84042240;
  if (ws_size < NEEDED) return;
  if (n_in < 23 || in_sizes[0] != 2097152 || in_sizes[3] != 16384 ||
      in_sizes[5] != 49152 || in_sizes[9] != 98304 || in_sizes[17] != 512 ||
      in_sizes[19] != 4096 || in_sizes[21] != 3584 || out_size != 2326528)
    return;

  char* ws = (char*)d_ws;
  bf*    arena = (bf*)(ws + OFF_ARENA);
  float* L     = (float*)(ws + OFF_ARENA);  // 7,864,320 B; valid after cell GRU
  int*   flag  = (int*)(ws + OFF_FLAG);
  bf*    x1    = (bf*)(ws + OFF_A);
  bf*    gi_c  = (bf*)(ws + OFF_A + 4194304);
  float* hw    = (float*)(ws + OFF_A);      // after steps (983,040 B)
  bf*    aggB  = (bf*)(ws + OFF_A + 983040);
  bf*    Wcat  = (bf*)(ws + OFF_WCAT);
  bf*    bcat  = (bf*)(ws + OFF_BCAT);
  bf*    W2p   = (bf*)(ws + OFF_W2P);
  bf*    hrnn  = (bf*)(ws + OFF_HRNN);
  bf*    G     = (bf*)(ws + OFF_G);

  float* out14 = (float*)d_out;
  float* outh  = (float*)d_out + 229376;

  kDetect<<<1, 1024, 0, stream>>>((const unsigned short*)d_in[0], flag);
  CArgs ca;
  for (int i = 0; i < 23; ++i) { ca.src[i] = d_in[i]; ca.n[i] = AN[i]; ca.off[i] = AO[i]; }
  kConvert<<<dim3(128, 23), 256, 0, stream>>>(ca, flag, arena);

  const bf* inputs = arena + AO[0];
  const bf* hidden = arena + AO[1];
  const bf* W1     = arena + AO[3];
  const bf* b1     = arena + AO[4];
  const bf* Wih_c  = arena + AO[5];
  const bf* Whh_c  = arena + AO[6];
  const bf* bih_c  = arena + AO[7];
  const bf* bhh_c  = arena + AO[8];
  const bf* Wih_f  = arena + AO[9];
  const bf* Whh_f  = arena + AO[10];
  const bf* bih_f  = arena + AO[11];
  const bf* bhh_f  = arena + AO[12];
  const bf* Wih_b  = arena + AO[13];
  const bf* Whh_b  = arena + AO[14];
  const bf* bih_b  = arena + AO[15];
  const bf* bhh_b  = arena + AO[16];
  const bf* Wq     = arena + AO[19];
  const bf* Wk     = arena + AO[20];
  const bf* W2a    = arena + AO[21];

  kPrep<<<dim3(800), 256, 0, stream>>>(Wih_f, bih_f, Wih_b, bih_b, Wq, Wk, W2a,
                                       Wcat, bcat, W2p);
  kGemm<<<dim3(256, 2), 256, 0, stream>>>(inputs, W1, b1, x1, 128, 1);
  kGemm<<<dim3(256, 6), 256, 0, stream>>>(x1, Wih_c, bih_c, gi_c, 384, 0);
  // cell GRU: h_rnn (bf16 + fp32 copy to d_out)
  kStep<<<dim3(256, 1, 2), 256, 0, stream>>>(hidden, Whh_c, gi_c, 384, bhh_c,
                                             hrnn, outh);
  // G = h_rnn @ Wcat^T + bcat
  kGemm<<<dim3(256, 25), 256, 0, stream>>>(hrnn, Wcat, bcat, G, 1600, 0);

  // fused 15-step bidirectional GRU -> L
  kSeq<<<dim3(1024), 256, 0, stream>>>(G, Whh_f, Whh_b, bhh_f, bhh_b,
                                       d_in[17], flag, L);

  kGumbel<<<dim3(960), 256, 0, stream>>>(L, d_in[2], flag, d_in[18], hw);
  kAttn<<<dim3(1024), 256, 0, stream>>>(hrnn, G, 1600, hw, aggB);
  kGemmOut<<<dim3(256), 256, 0, stream>>>(hrnn, aggB, W2p, d_in[22], flag, out14);
}

// Round 7
// 405.379 us; speedup vs baseline: 2.6606x; 1.9261x over previous
//
#include <hip/hip_runtime.h>
#include <hip/hip_bf16.h>

// G2AAgent — ROUND 7: kSeq v2.
//  Round-6 kSeq was 544us: FETCH 1.15GB (per-step Whh B-frag reloads missing
//  L2, 32-line scatter per load) + L partial-line write inflation.
//  Fixes: (a) dir-split blocks (1024x2), recurrent Whh B-frags held in VGPRs
//  (24 short8/wave, loaded once); (b) gi GEMM fused into kSeq (reads Wih_f/b
//  in place; G buffer + 66us store-bound kGemm deleted); (c) logits
//  accumulate in LDS, one aligned 64B-line write per row at the end.

typedef __attribute__((ext_vector_type(8))) short short8;
typedef __attribute__((ext_vector_type(4))) float float4v;

#define BF2F(x) __bfloat162float(x)
typedef __hip_bfloat16 bf;

__device__ __forceinline__ float fsigmoid(float x) {
  return 1.f / (1.f + __expf(-x));
}
__device__ __forceinline__ float ftanh(float x) {
  float ax = fabsf(x);
  float e = __expf(-2.f * ax);
  float t = (1.f - e) / (1.f + e);
  return x < 0.f ? -t : t;
}
__device__ __forceinline__ float rdv(const void* p, int i, int f) {
  return f ? ((const float*)p)[i] : BF2F(((const bf*)p)[i]);
}

// ---------------------------------------------------------------------------
static const int AO[23] = {
  0, 2097152, 4194304, 4685824, 4702208, 4702336, 4751488, 4800640, 4801024,
  4801408, 4899712, 4948864, 4949248, 4949632, 5047936, 5097088, 5097472,
  5097856, 5098368, 5098384, 5102480, 5106576, 5110160};
static const int AN[23] = {
  2097152, 2097152, 491520, 16384, 128, 49152, 49152, 384, 384, 98304, 49152,
  384, 384, 98304, 49152, 384, 384, 512, 2, 4096, 4096, 3584, 14};

struct CArgs {
  const void* src[23];
  int n[23];
  int off[23];
};

__global__ void kDetect(const unsigned short* __restrict__ p, int* flag) {
  __shared__ int s;
  if (threadIdx.x == 0) s = 0;
  __syncthreads();
  int hit = 0;
  for (int i = threadIdx.x; i < 4096; i += 1024) {
    int e = (p[i] >> 7) & 0xFF;
    if (e >= 0xC0) hit = 1;
  }
  if (hit) atomicOr(&s, 1);
  __syncthreads();
  if (threadIdx.x == 0) *flag = s;
}

__global__ void kConvert(CArgs a, const int* __restrict__ flag,
                         bf* __restrict__ arena) {
  const int b = blockIdx.y;
  const int n = a.n[b];
  const int f = *flag;
  bf* dst = arena + a.off[b];
  if (f) {
    const float* s = (const float*)a.src[b];
    for (int i = blockIdx.x * 256 + threadIdx.x; i < n; i += gridDim.x * 256)
      dst[i] = __float2bfloat16(s[i]);
  } else {
    const unsigned short* s = (const unsigned short*)a.src[b];
    unsigned short* d = (unsigned short*)dst;
    for (int i = blockIdx.x * 256 + threadIdx.x; i < n; i += gridDim.x * 256)
      d[i] = s[i];
  }
}

// ---------------------------------------------------------------------------
// kPrep: Wqk(64x128 = [Wq;Wk]) + W2p(16x256, rows 14/15 zero).
__global__ void kPrep(const bf* __restrict__ Wq, const bf* __restrict__ Wk,
                      const bf* __restrict__ W2a,
                      bf* __restrict__ Wqk, bf* __restrict__ W2p) {
  int idx = blockIdx.x * 256 + threadIdx.x;
  if (idx < 8192) {
    int r = idx >> 7, c = idx & 127;
    Wqk[idx] = (r < 32) ? Wq[r * 128 + c] : Wk[(r - 32) * 128 + c];
  }
  if (idx < 4096)
    W2p[idx] = (idx < 3584) ? W2a[idx] : __float2bfloat16(0.f);
}

// ---------------------------------------------------------------------------
// kGemm: out[M x N](bf16) = A[M x 128] @ W[N x 128]^T + bias, optional relu.
__global__ __launch_bounds__(256) void kGemm(const bf* __restrict__ A,
                                             const bf* __restrict__ W,
                                             const bf* __restrict__ bias,
                                             bf* __restrict__ out,
                                             int N, int relu) {
  const int tid = threadIdx.x;
  const int wave = tid >> 6, lane = tid & 63;
  const int quad = lane >> 4, ci = lane & 15;
  const int mr = blockIdx.x * 64 + wave * 16;
  const int nbase = blockIdx.y * 64;
  const int ntiles = (N - nbase < 64) ? ((N - nbase) >> 4) : 4;

  float4v acc[4];
#pragma unroll
  for (int i = 0; i < 4; ++i) acc[i] = {0.f, 0.f, 0.f, 0.f};

#pragma unroll
  for (int ks = 0; ks < 4; ++ks) {
    short8 a = *(const short8*)(A + (size_t)(mr + ci) * 128 + ks * 32 + quad * 8);
    for (int nt = 0; nt < ntiles; ++nt) {
      short8 b = *(const short8*)(W + (size_t)(nbase + nt * 16 + ci) * 128 + ks * 32 + quad * 8);
      acc[nt] = __builtin_amdgcn_mfma_f32_16x16x32_bf16(a, b, acc[nt], 0, 0, 0);
    }
  }

  for (int nt = 0; nt < ntiles; ++nt) {
    int col = nbase + nt * 16 + ci;
    float bv = bias ? BF2F(bias[col]) : 0.f;
#pragma unroll
    for (int r = 0; r < 4; ++r) {
      int row = mr + quad * 4 + r;
      float v = acc[nt][r] + bv;
      if (relu) v = fmaxf(v, 0.f);
      out[(size_t)row * N + col] = __float2bfloat16(v);
    }
  }
}

// ---------------------------------------------------------------------------
// kStep: single GRU step (cell GRU only).
__global__ __launch_bounds__(256, 4) void kStep(
    const bf* __restrict__ Hp, const bf* __restrict__ Whh,
    const bf* __restrict__ G, int gld,
    const bf* __restrict__ bhh,
    bf* __restrict__ Ho, float* __restrict__ HcopyF) {
  const int half = blockIdx.z;
  const int tid = threadIdx.x;
  const int wave = tid >> 6, lane = tid & 63;
  const int quad = lane >> 4, ci = lane & 15;
  const int mr = blockIdx.x * 64 + wave * 16;

  float4v acc[12];
#pragma unroll
  for (int i = 0; i < 12; ++i) acc[i] = {0.f, 0.f, 0.f, 0.f};

#pragma unroll
  for (int ks = 0; ks < 4; ++ks) {
    short8 a = *(const short8*)(Hp + (size_t)(mr + ci) * 128 + ks * 32 + quad * 8);
#pragma unroll
    for (int g = 0; g < 3; ++g)
#pragma unroll
      for (int nt = 0; nt < 4; ++nt) {
        short8 b = *(const short8*)(Whh + (size_t)(g * 128 + half * 64 + nt * 16 + ci) * 128 + ks * 32 + quad * 8);
        acc[g * 4 + nt] = __builtin_amdgcn_mfma_f32_16x16x32_bf16(a, b, acc[g * 4 + nt], 0, 0, 0);
      }
  }

  float bR[4], bZ[4], bN[4];
#pragma unroll
  for (int nt = 0; nt < 4; ++nt) {
    int c = half * 64 + nt * 16 + ci;
    bR[nt] = BF2F(bhh[c]);
    bZ[nt] = BF2F(bhh[128 + c]);
    bN[nt] = BF2F(bhh[256 + c]);
  }

#pragma unroll
  for (int r = 0; r < 4; ++r) {
    int rr = mr + quad * 4 + r;
    const bf* gs = G + (size_t)rr * gld;
#pragma unroll
    for (int nt = 0; nt < 4; ++nt) {
      int c = half * 64 + nt * 16 + ci;
      float gr = BF2F(gs[c]), gz = BF2F(gs[128 + c]), gnn = BF2F(gs[256 + c]);
      float pre_r = acc[nt][r] + gr + bR[nt];
      float pre_z = acc[4 + nt][r] + gz + bZ[nt];
      float hn_   = acc[8 + nt][r] + bN[nt];
      float rg = fsigmoid(pre_r);
      float zg = fsigmoid(pre_z);
      float ng = ftanh(gnn + rg * hn_);
      float hp = BF2F(Hp[(size_t)rr * 128 + c]);
      float hv = (1.f - zg) * ng + zg * hp;
      Ho[(size_t)rr * 128 + c] = __float2bfloat16(hv);
      if (HcopyF) HcopyF[(size_t)rr * 128 + c] = hv;
    }
  }
}

// ---------------------------------------------------------------------------
// kSeq v2: grid (1024, 2) = (env, dir), 256 thr = 4 waves (nh = 32-col quarter).
// Phase 1: gi = h_env @ Wih_d^T (self cols 0:128, nbr cols 128:256 in place)
//          -> sGiS/sGiN in LDS (+bih into self).
// Phase 2: load 24 persistent Whh B-frags into VGPRs.
// Phase 3: 15 steps, h ping-pong in LDS (stride 136), one barrier per step;
//          logit partials accumulate in sL, single write-out at the end.
__global__ __launch_bounds__(256, 2) void kSeq(
    const bf* __restrict__ hrnn,
    const bf* __restrict__ Wih_f, const bf* __restrict__ Wih_b,
    const bf* __restrict__ Whh_f, const bf* __restrict__ Whh_b,
    const bf* __restrict__ bih_f, const bf* __restrict__ bih_b,
    const bf* __restrict__ bhh_f, const bf* __restrict__ bhh_b,
    const void* __restrict__ WcRaw, const int* __restrict__ flagp,
    float* __restrict__ L) {
  __shared__ bf sGiS[16][384];        // self gi (+bih)           12 KB
  __shared__ bf sGiN[16][384];        // nbr gi                   12 KB
  __shared__ bf sH[2][16][136];       // h ping-pong              8.5 KB
  __shared__ float sL[16][15][4][2];  // logit partials per nh    7.5 KB

  const int env = blockIdx.x;
  const int dir = blockIdx.y;
  const int tid = threadIdx.x;
  const int wave = tid >> 6, lane = tid & 63;
  const int nh = wave;
  const int quad = lane >> 4, ci = lane & 15;
  const bf* Wih = dir ? Wih_b : Wih_f;
  const bf* Whh = dir ? Whh_b : Whh_f;
  const bf* bih = dir ? bih_b : bih_f;
  const bf* bhh = dir ? bhh_b : bhh_f;
  const int f = *flagp;

  // ---- Phase 1: gi GEMM (M=16, N=384 self + 384 nbr, K=128) ----
  {
    float4v gacc[12];
#pragma unroll
    for (int i = 0; i < 12; ++i) gacc[i] = {0.f, 0.f, 0.f, 0.f};
#pragma unroll
    for (int ks = 0; ks < 4; ++ks) {
      short8 a = *(const short8*)(hrnn + (size_t)(env * 16 + ci) * 128 + ks * 32 + quad * 8);
#pragma unroll
      for (int g6 = 0; g6 < 6; ++g6) {
        const bf* wrow = Wih + (size_t)(nh * 96 + g6 * 16 + ci) * 256 + ks * 32 + quad * 8;
        short8 bs = *(const short8*)(wrow);
        short8 bn = *(const short8*)(wrow + 128);
        gacc[g6]     = __builtin_amdgcn_mfma_f32_16x16x32_bf16(a, bs, gacc[g6], 0, 0, 0);
        gacc[6 + g6] = __builtin_amdgcn_mfma_f32_16x16x32_bf16(a, bn, gacc[6 + g6], 0, 0, 0);
      }
    }
#pragma unroll
    for (int g6 = 0; g6 < 6; ++g6) {
      int c = nh * 96 + g6 * 16 + ci;
      float bv = BF2F(bih[c]);
#pragma unroll
      for (int r = 0; r < 4; ++r) {
        int row = quad * 4 + r;
        sGiS[row][c] = __float2bfloat16(gacc[g6][r] + bv);
        sGiN[row][c] = __float2bfloat16(gacc[6 + g6][r]);
      }
    }
  }

  // zero h buffer 0
  {
    bf z = __float2bfloat16(0.f);
    bf* p = &sH[0][0][0];
    for (int i = tid; i < 2 * 16 * 136; i += 256) p[i] = z;
  }

  // ---- Phase 2: persistent Whh B-frags (96 VGPRs) + per-col constants ----
  short8 Bfrag[24];
#pragma unroll
  for (int g = 0; g < 3; ++g)
#pragma unroll
    for (int nt = 0; nt < 2; ++nt)
#pragma unroll
      for (int ks = 0; ks < 4; ++ks)
        Bfrag[(g * 2 + nt) * 4 + ks] =
            *(const short8*)(Whh + (size_t)(g * 128 + nh * 32 + nt * 16 + ci) * 128 + ks * 32 + quad * 8);

  float bR[2], bZ[2], bN[2], wc0[2], wc1[2];
#pragma unroll
  for (int nt = 0; nt < 2; ++nt) {
    int c = nh * 32 + nt * 16 + ci;
    bR[nt] = BF2F(bhh[c]);
    bZ[nt] = BF2F(bhh[128 + c]);
    bN[nt] = BF2F(bhh[256 + c]);
    wc0[nt] = rdv(WcRaw, dir * 128 + c, f);
    wc1[nt] = rdv(WcRaw, 256 + dir * 128 + c, f);
  }
  __syncthreads();

  // ---- Phase 3: 15 steps ----
  for (int t = 0; t < 15; ++t) {
    const int cur = t & 1, nxt = cur ^ 1;
    const int m = dir ? (14 - t) : t;

    float4v acc[6];
#pragma unroll
    for (int i = 0; i < 6; ++i) acc[i] = {0.f, 0.f, 0.f, 0.f};
#pragma unroll
    for (int ks = 0; ks < 4; ++ks) {
      short8 a = *(const short8*)&sH[cur][ci][ks * 32 + quad * 8];
#pragma unroll
      for (int tl = 0; tl < 6; ++tl)
        acc[tl] = __builtin_amdgcn_mfma_f32_16x16x32_bf16(a, Bfrag[tl * 4 + ks], acc[tl], 0, 0, 0);
    }

#pragma unroll
    for (int r_ = 0; r_ < 4; ++r_) {
      int row = quad * 4 + r_;
      int jr = m + ((m >= row) ? 1 : 0);
      float pl0 = 0.f, pl1 = 0.f;
#pragma unroll
      for (int nt = 0; nt < 2; ++nt) {
        int c = nh * 32 + nt * 16 + ci;
        float gr  = BF2F(sGiS[row][c])       + BF2F(sGiN[jr][c]);
        float gz  = BF2F(sGiS[row][128 + c]) + BF2F(sGiN[jr][128 + c]);
        float gnn = BF2F(sGiS[row][256 + c]) + BF2F(sGiN[jr][256 + c]);
        float pre_r = acc[nt][r_] + gr + bR[nt];
        float pre_z = acc[2 + nt][r_] + gz + bZ[nt];
        float hn_   = acc[4 + nt][r_] + bN[nt];
        float rg = fsigmoid(pre_r);
        float zg = fsigmoid(pre_z);
        float ng = ftanh(gnn + rg * hn_);
        float hp = BF2F(sH[cur][row][c]);
        float hv = (1.f - zg) * ng + zg * hp;
        sH[nxt][row][c] = __float2bfloat16(hv);
        pl0 += hv * wc0[nt];
        pl1 += hv * wc1[nt];
      }
#pragma unroll
      for (int d = 1; d < 16; d <<= 1) {
        pl0 += __shfl_xor(pl0, d);
        pl1 += __shfl_xor(pl1, d);
      }
      if (ci == 0) {
        sL[row][m][nh][0] = pl0;
        sL[row][m][nh][1] = pl1;
      }
    }
    __syncthreads();
  }

  // ---- write-out logits: L[(row16*15+m)*4 + dir*2 + l] ----
  for (int i = tid; i < 480; i += 256) {
    int row = i / 30, rem = i - row * 30;
    int mm = rem >> 1, l = rem & 1;
    float v = sL[row][mm][0][l] + sL[row][mm][1][l] +
              sL[row][mm][2][l] + sL[row][mm][3][l];
    L[(size_t)((env * 16 + row) * 15 + mm) * 4 + dir * 2 + l] = v;
  }
}

// ---------------------------------------------------------------------------
// kGumbel: hard_w = sigmoid(((l1+g1)-(l0+g0)) / TAU), TAU=0.5. Sums 2 dirs.
__global__ void kGumbel(const float* __restrict__ L, const void* __restrict__ guRaw,
                        const int* __restrict__ flag, const void* __restrict__ bcRaw,
                        float* __restrict__ hw) {
  int idx = blockIdx.x * 256 + threadIdx.x;
  if (idx >= 245760) return;
  const int f = *flag;
  const float* Lp = L + (size_t)idx * 4;
  float l0 = Lp[0] + Lp[2] + rdv(bcRaw, 0, f);
  float l1 = Lp[1] + Lp[3] + rdv(bcRaw, 1, f);
  float u0 = rdv(guRaw, idx * 2, f);
  float u1 = rdv(guRaw, idx * 2 + 1, f);
  float g0 = -__logf(-__logf(u0 + 1e-10f) + 1e-10f);
  float g1 = -__logf(-__logf(u1 + 1e-10f) + 1e-10f);
  float d = ((l1 + g1) - (l0 + g0)) * 2.0f;
  hw[idx] = fsigmoid(d);
}

// ---------------------------------------------------------------------------
// kAttn: per-env attention; writes agg (bf16, 16384x128). qk = 16384x64.
__global__ __launch_bounds__(256) void kAttn(
    const bf* __restrict__ h, const bf* __restrict__ qk,
    const float* __restrict__ hw, bf* __restrict__ aggB) {
  __shared__ float sh[16 * 132];
  __shared__ float sqk[16 * 64];
  __shared__ float shw[16 * 15];
  __shared__ float sw[16 * 16];
  int bb = blockIdx.x, tid = threadIdx.x;

  for (int i = tid; i < 2048; i += 256)
    sh[(i >> 7) * 132 + (i & 127)] = BF2F(h[(size_t)bb * 2048 + i]);
  for (int i = tid; i < 1024; i += 256)
    sqk[i] = BF2F(qk[(size_t)bb * 1024 + i]);
  for (int i = tid; i < 240; i += 256) shw[i] = hw[bb * 240 + i];
  __syncthreads();

  int a = tid >> 4, i = tid & 15;
  float s = -1e30f;
  if (i < 15) {
    int j = i + (i >= a);
    float d = 0.f;
#pragma unroll
    for (int c = 0; c < 32; ++c) d += sqk[a * 64 + c] * sqk[j * 64 + 32 + c];
    s = shw[a * 15 + i] * d * 0.17677669529663687f;
  }
  float mx = s;
#pragma unroll
  for (int d = 1; d < 16; d <<= 1) mx = fmaxf(mx, __shfl_xor(mx, d));
  float e = (i < 15) ? __expf(s - mx) : 0.f;
  float sum = e;
#pragma unroll
  for (int d = 1; d < 16; d <<= 1) sum += __shfl_xor(sum, d);
  float w = (i < 15) ? (e / sum) * shw[a * 15 + i] : 0.f;
  sw[a * 16 + i] = w;
  __syncthreads();

  float ac[8] = {0, 0, 0, 0, 0, 0, 0, 0};
  for (int mm = 0; mm < 15; ++mm) {
    int jm = mm + (mm >= a);
    float wm = sw[a * 16 + mm];
    const float* shp = &sh[jm * 132 + i * 8];
    float4 h0 = *(const float4*)shp;
    float4 h1 = *(const float4*)(shp + 4);
    ac[0] += wm * h0.x; ac[1] += wm * h0.y; ac[2] += wm * h0.z; ac[3] += wm * h0.w;
    ac[4] += wm * h1.x; ac[5] += wm * h1.y; ac[6] += wm * h1.z; ac[7] += wm * h1.w;
  }
  short8 v;
#pragma unroll
  for (int d = 0; d < 8; ++d) {
    bf b = __float2bfloat16(ac[d]);
    v[d] = *(short*)&b;
  }
  *(short8*)(aggB + (size_t)(bb * 16 + a) * 128 + i * 8) = v;
}

// ---------------------------------------------------------------------------
// kGemmOut: out14[16384 x 14] (fp32) = [h_rnn, agg] @ W2p^T + b2.
__global__ __launch_bounds__(256) void kGemmOut(
    const bf* __restrict__ hrnn, const bf* __restrict__ aggB,
    const bf* __restrict__ W2p, const void* __restrict__ b2Raw,
    const int* __restrict__ flag, float* __restrict__ out) {
  const int tid = threadIdx.x;
  const int wave = tid >> 6, lane = tid & 63;
  const int quad = lane >> 4, ci = lane & 15;
  const int mr = blockIdx.x * 64 + wave * 16;
  const int f = *flag;

  float4v acc = {0.f, 0.f, 0.f, 0.f};
#pragma unroll
  for (int ks = 0; ks < 8; ++ks) {
    const bf* src = (ks < 4) ? hrnn : aggB;
    int k = (ks & 3) * 32 + quad * 8;
    short8 a = *(const short8*)(src + (size_t)(mr + ci) * 128 + k);
    short8 b = *(const short8*)(W2p + (size_t)ci * 256 + ks * 32 + quad * 8);
    acc = __builtin_amdgcn_mfma_f32_16x16x32_bf16(a, b, acc, 0, 0, 0);
  }

  if (ci < 14) {
    float bv = rdv(b2Raw, ci, f);
#pragma unroll
    for (int r = 0; r < 4; ++r)
      out[(size_t)(mr + quad * 4 + r) * 14 + ci] = acc[r] + bv;
  }
}

// ---------------------------------------------------------------------------
extern "C" void kernel_launch(void* const* d_in, const int* in_sizes, int n_in,
                              void* d_out, int out_size, void* d_ws, size_t ws_size,
                              hipStream_t stream) {
  const size_t OFF_ARENA = 0;          // bf16 arena; L (3.93MB) overlaps dead
                                       //   inputs+hidden [0, 8.38MB) after cell
  const size_t OFF_FLAG  = 10220544;
  const size_t OFF_A     = 10220800;   // x1+gi_c -> hw+agg
  const size_t OFF_WQK   = 26998016;   // 16 KB
  const size_t OFF_W2P   = 27410944;   // 8 KB
  const size_t OFF_HRNN  = 27419136;   // 4 MB
  const size_t OFF_QK    = 31613440;   // 2 MB (old G region)
  const size_t NEEDED    = 84042240;
  if (ws_size < NEEDED) return;
  if (n_in < 23 || in_sizes[0] != 2097152 || in_sizes[3] != 16384 ||
      in_sizes[5] != 49152 || in_sizes[9] != 98304 || in_sizes[17] != 512 ||
      in_sizes[19] != 4096 || in_sizes[21] != 3584 || out_size != 2326528)
    return;

  char* ws = (char*)d_ws;
  bf*    arena = (bf*)(ws + OFF_ARENA);
  float* L     = (float*)(ws + OFF_ARENA);  // 3.93 MB; valid after cell GRU
  int*   flag  = (int*)(ws + OFF_FLAG);
  bf*    x1    = (bf*)(ws + OFF_A);
  bf*    gi_c  = (bf*)(ws + OFF_A + 4194304);
  float* hw    = (float*)(ws + OFF_A);      // after kSeq (983 KB)
  bf*    aggB  = (bf*)(ws + OFF_A + 983040);
  bf*    Wqk   = (bf*)(ws + OFF_WQK);
  bf*    W2p   = (bf*)(ws + OFF_W2P);
  bf*    hrnn  = (bf*)(ws + OFF_HRNN);
  bf*    qk    = (bf*)(ws + OFF_QK);

  float* out14 = (float*)d_out;
  float* outh  = (float*)d_out + 229376;

  kDetect<<<1, 1024, 0, stream>>>((const unsigned short*)d_in[0], flag);
  CArgs ca;
  for (int i = 0; i < 23; ++i) { ca.src[i] = d_in[i]; ca.n[i] = AN[i]; ca.off[i] = AO[i]; }
  kConvert<<<dim3(128, 23), 256, 0, stream>>>(ca, flag, arena);

  const bf* inputs = arena + AO[0];
  const bf* hidden = arena + AO[1];
  const bf* W1     = arena + AO[3];
  const bf* b1     = arena + AO[4];
  const bf* Wih_c  = arena + AO[5];
  const bf* Whh_c  = arena + AO[6];
  const bf* bih_c  = arena + AO[7];
  const bf* bhh_c  = arena + AO[8];
  const bf* Wih_f  = arena + AO[9];
  const bf* Whh_f  = arena + AO[10];
  const bf* bih_f  = arena + AO[11];
  const bf* bhh_f  = arena + AO[12];
  const bf* Wih_b  = arena + AO[13];
  const bf* Whh_b  = arena + AO[14];
  const bf* bih_b  = arena + AO[15];
  const bf* bhh_b  = arena + AO[16];
  const bf* Wq     = arena + AO[19];
  const bf* Wk     = arena + AO[20];
  const bf* W2a    = arena + AO[21];

  kPrep<<<dim3(32), 256, 0, stream>>>(Wq, Wk, W2a, Wqk, W2p);
  kGemm<<<dim3(256, 2), 256, 0, stream>>>(inputs, W1, b1, x1, 128, 1);
  kGemm<<<dim3(256, 6), 256, 0, stream>>>(x1, Wih_c, bih_c, gi_c, 384, 0);
  // cell GRU: h_rnn (bf16 + fp32 copy to d_out)
  kStep<<<dim3(256, 1, 2), 256, 0, stream>>>(hidden, Whh_c, gi_c, 384, bhh_c,
                                             hrnn, outh);
  // qk = h_rnn @ [Wq;Wk]^T  (16384 x 64)
  kGemm<<<dim3(256, 1), 256, 0, stream>>>(hrnn, Wqk, (const bf*)nullptr, qk, 64, 0);

  // fused gi-GEMM + 15-step bidirectional GRU -> L
  kSeq<<<dim3(1024, 2), 256, 0, stream>>>(hrnn, Wih_f, Wih_b, Whh_f, Whh_b,
                                          bih_f, bih_b, bhh_f, bhh_b,
                                          d_in[17], flag, L);

  kGumbel<<<dim3(960), 256, 0, stream>>>(L, d_in[2], flag, d_in[18], hw);
  kAttn<<<dim3(1024), 256, 0, stream>>>(hrnn, qk, hw, aggB);
  kGemmOut<<<dim3(256), 256, 0, stream>>>(hrnn, aggB, W2p, d_in[22], flag, out14);
}

// Round 8
// 374.626 us; speedup vs baseline: 2.8790x; 1.0821x over previous
//
#include <hip/hip_runtime.h>
#include <hip/hip_bf16.h>

// G2AAgent — ROUND 8: kSeq v3 (LDS-pipe diet).
//  Round-7 kSeq (233us) was LDS-pipe-bound: ~48 ds_read_u16 + 32 ds_bpermute
//  (shfl logit reduce) per thread per step. Fixes:
//   (a) phase-1 retiled so self-gi stays in 24 VGPRs (fp32, +bih folded);
//   (b) nbr-gi packed 3-gates-per-u64 -> 8 ds_read_b64 instead of 24 u16;
//   (c) logits via an extra MFMA tile vs zero-padded Wc B-frag (reuses the
//       recurrent A-frags, pipelined one step behind) -> zero ds_bpermute.

typedef __attribute__((ext_vector_type(8))) short short8;
typedef __attribute__((ext_vector_type(4))) float float4v;

#define BF2F(x) __bfloat162float(x)
typedef __hip_bfloat16 bf;

__device__ __forceinline__ float fsigmoid(float x) {
  return 1.f / (1.f + __expf(-x));
}
__device__ __forceinline__ float ftanh(float x) {
  float ax = fabsf(x);
  float e = __expf(-2.f * ax);
  float t = (1.f - e) / (1.f + e);
  return x < 0.f ? -t : t;
}
__device__ __forceinline__ float rdv(const void* p, int i, int f) {
  return f ? ((const float*)p)[i] : BF2F(((const bf*)p)[i]);
}
__device__ __forceinline__ float upk(unsigned long long v, int s) {
  union { unsigned int i; float f; } x;
  x.i = ((unsigned int)((v >> s) & 0xffffULL)) << 16;
  return x.f;
}

// ---------------------------------------------------------------------------
static const int AO[23] = {
  0, 2097152, 4194304, 4685824, 4702208, 4702336, 4751488, 4800640, 4801024,
  4801408, 4899712, 4948864, 4949248, 4949632, 5047936, 5097088, 5097472,
  5097856, 5098368, 5098384, 5102480, 5106576, 5110160};
static const int AN[23] = {
  2097152, 2097152, 491520, 16384, 128, 49152, 49152, 384, 384, 98304, 49152,
  384, 384, 98304, 49152, 384, 384, 512, 2, 4096, 4096, 3584, 14};

struct CArgs {
  const void* src[23];
  int n[23];
  int off[23];
};

__global__ void kDetect(const unsigned short* __restrict__ p, int* flag) {
  __shared__ int s;
  if (threadIdx.x == 0) s = 0;
  __syncthreads();
  int hit = 0;
  for (int i = threadIdx.x; i < 4096; i += 1024) {
    int e = (p[i] >> 7) & 0xFF;
    if (e >= 0xC0) hit = 1;
  }
  if (hit) atomicOr(&s, 1);
  __syncthreads();
  if (threadIdx.x == 0) *flag = s;
}

__global__ void kConvert(CArgs a, const int* __restrict__ flag,
                         bf* __restrict__ arena) {
  const int b = blockIdx.y;
  const int n = a.n[b];
  const int f = *flag;
  bf* dst = arena + a.off[b];
  if (f) {
    const float* s = (const float*)a.src[b];
    for (int i = blockIdx.x * 256 + threadIdx.x; i < n; i += gridDim.x * 256)
      dst[i] = __float2bfloat16(s[i]);
  } else {
    const unsigned short* s = (const unsigned short*)a.src[b];
    unsigned short* d = (unsigned short*)dst;
    for (int i = blockIdx.x * 256 + threadIdx.x; i < n; i += gridDim.x * 256)
      d[i] = s[i];
  }
}

// ---------------------------------------------------------------------------
// kPrep: Wqk(64x128=[Wq;Wk]), W2p(16x256, rows 14/15 zero),
//        Wcb(2dir x 2logit x 128) from Wc arena.
__global__ void kPrep(const bf* __restrict__ Wq, const bf* __restrict__ Wk,
                      const bf* __restrict__ W2a, const bf* __restrict__ WcA,
                      bf* __restrict__ Wqk, bf* __restrict__ W2p,
                      bf* __restrict__ Wcb) {
  int idx = blockIdx.x * 256 + threadIdx.x;
  if (idx < 8192) {
    int r = idx >> 7, c = idx & 127;
    Wqk[idx] = (r < 32) ? Wq[r * 128 + c] : Wk[(r - 32) * 128 + c];
  }
  if (idx < 4096)
    W2p[idx] = (idx < 3584) ? W2a[idx] : __float2bfloat16(0.f);
  if (idx < 512) {
    int dir = idx >> 8, l = (idx >> 7) & 1, k = idx & 127;
    Wcb[idx] = WcA[l * 256 + dir * 128 + k];
  }
}

// ---------------------------------------------------------------------------
// kGemm: out[M x N](bf16) = A[M x 128] @ W[N x 128]^T + bias, optional relu.
__global__ __launch_bounds__(256) void kGemm(const bf* __restrict__ A,
                                             const bf* __restrict__ W,
                                             const bf* __restrict__ bias,
                                             bf* __restrict__ out,
                                             int N, int relu) {
  const int tid = threadIdx.x;
  const int wave = tid >> 6, lane = tid & 63;
  const int quad = lane >> 4, ci = lane & 15;
  const int mr = blockIdx.x * 64 + wave * 16;
  const int nbase = blockIdx.y * 64;
  const int ntiles = (N - nbase < 64) ? ((N - nbase) >> 4) : 4;

  float4v acc[4];
#pragma unroll
  for (int i = 0; i < 4; ++i) acc[i] = {0.f, 0.f, 0.f, 0.f};

#pragma unroll
  for (int ks = 0; ks < 4; ++ks) {
    short8 a = *(const short8*)(A + (size_t)(mr + ci) * 128 + ks * 32 + quad * 8);
    for (int nt = 0; nt < ntiles; ++nt) {
      short8 b = *(const short8*)(W + (size_t)(nbase + nt * 16 + ci) * 128 + ks * 32 + quad * 8);
      acc[nt] = __builtin_amdgcn_mfma_f32_16x16x32_bf16(a, b, acc[nt], 0, 0, 0);
    }
  }

  for (int nt = 0; nt < ntiles; ++nt) {
    int col = nbase + nt * 16 + ci;
    float bv = bias ? BF2F(bias[col]) : 0.f;
#pragma unroll
    for (int r = 0; r < 4; ++r) {
      int row = mr + quad * 4 + r;
      float v = acc[nt][r] + bv;
      if (relu) v = fmaxf(v, 0.f);
      out[(size_t)row * N + col] = __float2bfloat16(v);
    }
  }
}

// ---------------------------------------------------------------------------
// kStep: single GRU step (cell GRU only).
__global__ __launch_bounds__(256, 4) void kStep(
    const bf* __restrict__ Hp, const bf* __restrict__ Whh,
    const bf* __restrict__ G, int gld,
    const bf* __restrict__ bhh,
    bf* __restrict__ Ho, float* __restrict__ HcopyF) {
  const int half = blockIdx.z;
  const int tid = threadIdx.x;
  const int wave = tid >> 6, lane = tid & 63;
  const int quad = lane >> 4, ci = lane & 15;
  const int mr = blockIdx.x * 64 + wave * 16;

  float4v acc[12];
#pragma unroll
  for (int i = 0; i < 12; ++i) acc[i] = {0.f, 0.f, 0.f, 0.f};

#pragma unroll
  for (int ks = 0; ks < 4; ++ks) {
    short8 a = *(const short8*)(Hp + (size_t)(mr + ci) * 128 + ks * 32 + quad * 8);
#pragma unroll
    for (int g = 0; g < 3; ++g)
#pragma unroll
      for (int nt = 0; nt < 4; ++nt) {
        short8 b = *(const short8*)(Whh + (size_t)(g * 128 + half * 64 + nt * 16 + ci) * 128 + ks * 32 + quad * 8);
        acc[g * 4 + nt] = __builtin_amdgcn_mfma_f32_16x16x32_bf16(a, b, acc[g * 4 + nt], 0, 0, 0);
      }
  }

  float bR[4], bZ[4], bN[4];
#pragma unroll
  for (int nt = 0; nt < 4; ++nt) {
    int c = half * 64 + nt * 16 + ci;
    bR[nt] = BF2F(bhh[c]);
    bZ[nt] = BF2F(bhh[128 + c]);
    bN[nt] = BF2F(bhh[256 + c]);
  }

#pragma unroll
  for (int r = 0; r < 4; ++r) {
    int rr = mr + quad * 4 + r;
    const bf* gs = G + (size_t)rr * gld;
#pragma unroll
    for (int nt = 0; nt < 4; ++nt) {
      int c = half * 64 + nt * 16 + ci;
      float gr = BF2F(gs[c]), gz = BF2F(gs[128 + c]), gnn = BF2F(gs[256 + c]);
      float pre_r = acc[nt][r] + gr + bR[nt];
      float pre_z = acc[4 + nt][r] + gz + bZ[nt];
      float hn_   = acc[8 + nt][r] + bN[nt];
      float rg = fsigmoid(pre_r);
      float zg = fsigmoid(pre_z);
      float ng = ftanh(gnn + rg * hn_);
      float hp = BF2F(Hp[(size_t)rr * 128 + c]);
      float hv = (1.f - zg) * ng + zg * hp;
      Ho[(size_t)rr * 128 + c] = __float2bfloat16(hv);
      if (HcopyF) HcopyF[(size_t)rr * 128 + c] = hv;
    }
  }
}

// ---------------------------------------------------------------------------
// kSeq v3: grid (1024, 2) = (env, dir), 256 thr = 4 waves (nh = 32-col quarter).
// Phase 1: gi GEMM retiled so each thread's self-gi C-layout cols == its step
//   epilogue cols -> self-gi lives in 24 VGPRs (fp32, +bih). Nbr-gi packed
//   3-gates-per-u64 into sGiN. Phase 2: 24 persistent Whh B-frags in VGPRs +
//   Wc B-frag (lanes ci<2). Phase 3: 15 steps; logits of h_{t-1} via one MFMA
//   tile in step t (wave nh0), tail MFMA for h_14; sL dumped once.
__global__ __launch_bounds__(256, 2) void kSeq(
    const bf* __restrict__ hrnn,
    const bf* __restrict__ Wih_f, const bf* __restrict__ Wih_b,
    const bf* __restrict__ Whh_f, const bf* __restrict__ Whh_b,
    const bf* __restrict__ bih_f, const bf* __restrict__ bih_b,
    const bf* __restrict__ bhh_f, const bf* __restrict__ bhh_b,
    const bf* __restrict__ Wcb, float* __restrict__ L) {
  __shared__ unsigned long long sGiN[16][130];  // [row][col] 3 bf16 gates  16.6 KB
  __shared__ bf sH[2][16][136];                 // h ping-pong               8.7 KB
  __shared__ float sL[16][15][2];               // logits                    1.9 KB

  const int env = blockIdx.x;
  const int dir = blockIdx.y;
  const int tid = threadIdx.x;
  const int wave = tid >> 6, lane = tid & 63;
  const int nh = wave;
  const int quad = lane >> 4, ci = lane & 15;
  const bf* Wih = dir ? Wih_b : Wih_f;
  const bf* Whh = dir ? Whh_b : Whh_f;
  const bf* bih = dir ? bih_b : bih_f;
  const bf* bhh = dir ? bhh_b : bhh_f;

  // ---- Phase 1: gi GEMM. Tiles: gate(3) x nt(2); B row = gate*128+nh*32+nt*16.
  float4v gS[6], gN[6];
#pragma unroll
  for (int i = 0; i < 6; ++i) { gS[i] = {0.f, 0.f, 0.f, 0.f}; gN[i] = {0.f, 0.f, 0.f, 0.f}; }
#pragma unroll
  for (int ks = 0; ks < 4; ++ks) {
    short8 a = *(const short8*)(hrnn + (size_t)(env * 16 + ci) * 128 + ks * 32 + quad * 8);
#pragma unroll
    for (int g = 0; g < 3; ++g)
#pragma unroll
      for (int nt = 0; nt < 2; ++nt) {
        const bf* wrow = Wih + (size_t)(g * 128 + nh * 32 + nt * 16 + ci) * 256 + ks * 32 + quad * 8;
        short8 bs = *(const short8*)(wrow);
        short8 bn = *(const short8*)(wrow + 128);
        gS[g * 2 + nt] = __builtin_amdgcn_mfma_f32_16x16x32_bf16(a, bs, gS[g * 2 + nt], 0, 0, 0);
        gN[g * 2 + nt] = __builtin_amdgcn_mfma_f32_16x16x32_bf16(a, bn, gN[g * 2 + nt], 0, 0, 0);
      }
  }
  // fold bih into self-gi (stays in regs); pack nbr-gi into sGiN
#pragma unroll
  for (int g = 0; g < 3; ++g)
#pragma unroll
    for (int nt = 0; nt < 2; ++nt) {
      float bv = BF2F(bih[g * 128 + nh * 32 + nt * 16 + ci]);
#pragma unroll
      for (int r = 0; r < 4; ++r) gS[g * 2 + nt][r] += bv;
    }
#pragma unroll
  for (int nt = 0; nt < 2; ++nt)
#pragma unroll
    for (int r = 0; r < 4; ++r) {
      unsigned long long pk = 0;
#pragma unroll
      for (int g = 0; g < 3; ++g) {
        bf b = __float2bfloat16(gN[g * 2 + nt][r]);
        pk |= ((unsigned long long)(*(unsigned short*)&b)) << (16 * g);
      }
      sGiN[quad * 4 + r][nh * 32 + nt * 16 + ci] = pk;
    }

  // zero h buffer 0
  {
    bf z = __float2bfloat16(0.f);
    bf* p = &sH[0][0][0];
    for (int i = tid; i < 16 * 136; i += 256) p[i] = z;
  }

  // ---- Phase 2: persistent Whh B-frags (96 VGPRs), Wc frag, constants ----
  short8 Bf[24];
#pragma unroll
  for (int g = 0; g < 3; ++g)
#pragma unroll
    for (int nt = 0; nt < 2; ++nt)
#pragma unroll
      for (int ks = 0; ks < 4; ++ks)
        Bf[(g * 2 + nt) * 4 + ks] =
            *(const short8*)(Whh + (size_t)(g * 128 + nh * 32 + nt * 16 + ci) * 128 + ks * 32 + quad * 8);

  short8 wcf[4];
#pragma unroll
  for (int ks = 0; ks < 4; ++ks) {
    if (ci < 2)
      wcf[ks] = *(const short8*)(Wcb + (size_t)(dir * 2 + ci) * 128 + ks * 32 + quad * 8);
    else
      wcf[ks] = short8{0, 0, 0, 0, 0, 0, 0, 0};
  }

  float bR[2], bZ[2], bNc[2];
#pragma unroll
  for (int nt = 0; nt < 2; ++nt) {
    int c = nh * 32 + nt * 16 + ci;
    bR[nt] = BF2F(bhh[c]);
    bZ[nt] = BF2F(bhh[128 + c]);
    bNc[nt] = BF2F(bhh[256 + c]);
  }
  __syncthreads();

  // ---- Phase 3: 15 steps ----
  for (int t = 0; t < 15; ++t) {
    const int cur = t & 1, nxt = cur ^ 1;
    const int m = dir ? (14 - t) : t;

    float4v acc[6];
#pragma unroll
    for (int i = 0; i < 6; ++i) acc[i] = {0.f, 0.f, 0.f, 0.f};
    float4v lacc = {0.f, 0.f, 0.f, 0.f};
#pragma unroll
    for (int ks = 0; ks < 4; ++ks) {
      short8 a = *(const short8*)&sH[cur][ci][ks * 32 + quad * 8];
#pragma unroll
      for (int tl = 0; tl < 6; ++tl)
        acc[tl] = __builtin_amdgcn_mfma_f32_16x16x32_bf16(a, Bf[tl * 4 + ks], acc[tl], 0, 0, 0);
      if (nh == 0)
        lacc = __builtin_amdgcn_mfma_f32_16x16x32_bf16(a, wcf[ks], lacc, 0, 0, 0);
    }
    if (nh == 0 && t > 0 && ci < 2) {
      int mp = dir ? (15 - t) : (t - 1);   // m of step t-1
#pragma unroll
      for (int r = 0; r < 4; ++r) sL[quad * 4 + r][mp][ci] = lacc[r];
    }

#pragma unroll
    for (int r_ = 0; r_ < 4; ++r_) {
      int row = quad * 4 + r_;
      int jr = m + ((m >= row) ? 1 : 0);
#pragma unroll
      for (int nt = 0; nt < 2; ++nt) {
        int c = nh * 32 + nt * 16 + ci;
        unsigned long long nb = sGiN[jr][c];
        float gr  = gS[nt][r_]     + upk(nb, 0);
        float gz  = gS[2 + nt][r_] + upk(nb, 16);
        float gnn = gS[4 + nt][r_] + upk(nb, 32);
        float pre_r = acc[nt][r_] + gr + bR[nt];
        float pre_z = acc[2 + nt][r_] + gz + bZ[nt];
        float hn_   = acc[4 + nt][r_] + bNc[nt];
        float rg = fsigmoid(pre_r);
        float zg = fsigmoid(pre_z);
        float ng = ftanh(gnn + rg * hn_);
        float hp = BF2F(sH[cur][row][c]);
        float hv = (1.f - zg) * ng + zg * hp;
        sH[nxt][row][c] = __float2bfloat16(hv);
      }
    }
    __syncthreads();
  }

  // tail: logits of h_14 (in sH[1])
  if (nh == 0) {
    float4v lacc = {0.f, 0.f, 0.f, 0.f};
#pragma unroll
    for (int ks = 0; ks < 4; ++ks) {
      short8 a = *(const short8*)&sH[1][ci][ks * 32 + quad * 8];
      lacc = __builtin_amdgcn_mfma_f32_16x16x32_bf16(a, wcf[ks], lacc, 0, 0, 0);
    }
    if (ci < 2) {
      int mf = dir ? 0 : 14;
#pragma unroll
      for (int r = 0; r < 4; ++r) sL[quad * 4 + r][mf][ci] = lacc[r];
    }
  }
  __syncthreads();

  for (int i = tid; i < 480; i += 256) {
    int row = i / 30, rem = i - row * 30;
    int mm = rem >> 1, l = rem & 1;
    L[(size_t)((env * 16 + row) * 15 + mm) * 4 + dir * 2 + l] = sL[row][mm][l];
  }
}

// ---------------------------------------------------------------------------
// kGumbel: hard_w = sigmoid(((l1+g1)-(l0+g0)) / TAU), TAU=0.5. Sums 2 dirs.
__global__ void kGumbel(const float* __restrict__ L, const void* __restrict__ guRaw,
                        const int* __restrict__ flag, const void* __restrict__ bcRaw,
                        float* __restrict__ hw) {
  int idx = blockIdx.x * 256 + threadIdx.x;
  if (idx >= 245760) return;
  const int f = *flag;
  const float* Lp = L + (size_t)idx * 4;
  float l0 = Lp[0] + Lp[2] + rdv(bcRaw, 0, f);
  float l1 = Lp[1] + Lp[3] + rdv(bcRaw, 1, f);
  float u0 = rdv(guRaw, idx * 2, f);
  float u1 = rdv(guRaw, idx * 2 + 1, f);
  float g0 = -__logf(-__logf(u0 + 1e-10f) + 1e-10f);
  float g1 = -__logf(-__logf(u1 + 1e-10f) + 1e-10f);
  float d = ((l1 + g1) - (l0 + g0)) * 2.0f;
  hw[idx] = fsigmoid(d);
}

// ---------------------------------------------------------------------------
// kAttn: per-env attention; writes agg (bf16, 16384x128). qk = 16384x64.
__global__ __launch_bounds__(256) void kAttn(
    const bf* __restrict__ h, const bf* __restrict__ qk,
    const float* __restrict__ hw, bf* __restrict__ aggB) {
  __shared__ float sh[16 * 132];
  __shared__ float sqk[16 * 64];
  __shared__ float shw[16 * 15];
  __shared__ float sw[16 * 16];
  int bb = blockIdx.x, tid = threadIdx.x;

  for (int i = tid; i < 2048; i += 256)
    sh[(i >> 7) * 132 + (i & 127)] = BF2F(h[(size_t)bb * 2048 + i]);
  for (int i = tid; i < 1024; i += 256)
    sqk[i] = BF2F(qk[(size_t)bb * 1024 + i]);
  for (int i = tid; i < 240; i += 256) shw[i] = hw[bb * 240 + i];
  __syncthreads();

  int a = tid >> 4, i = tid & 15;
  float s = -1e30f;
  if (i < 15) {
    int j = i + (i >= a);
    float d = 0.f;
#pragma unroll
    for (int c = 0; c < 32; ++c) d += sqk[a * 64 + c] * sqk[j * 64 + 32 + c];
    s = shw[a * 15 + i] * d * 0.17677669529663687f;
  }
  float mx = s;
#pragma unroll
  for (int d = 1; d < 16; d <<= 1) mx = fmaxf(mx, __shfl_xor(mx, d));
  float e = (i < 15) ? __expf(s - mx) : 0.f;
  float sum = e;
#pragma unroll
  for (int d = 1; d < 16; d <<= 1) sum += __shfl_xor(sum, d);
  float w = (i < 15) ? (e / sum) * shw[a * 15 + i] : 0.f;
  sw[a * 16 + i] = w;
  __syncthreads();

  float ac[8] = {0, 0, 0, 0, 0, 0, 0, 0};
  for (int mm = 0; mm < 15; ++mm) {
    int jm = mm + (mm >= a);
    float wm = sw[a * 16 + mm];
    const float* shp = &sh[jm * 132 + i * 8];
    float4 h0 = *(const float4*)shp;
    float4 h1 = *(const float4*)(shp + 4);
    ac[0] += wm * h0.x; ac[1] += wm * h0.y; ac[2] += wm * h0.z; ac[3] += wm * h0.w;
    ac[4] += wm * h1.x; ac[5] += wm * h1.y; ac[6] += wm * h1.z; ac[7] += wm * h1.w;
  }
  short8 v;
#pragma unroll
  for (int d = 0; d < 8; ++d) {
    bf b = __float2bfloat16(ac[d]);
    v[d] = *(short*)&b;
  }
  *(short8*)(aggB + (size_t)(bb * 16 + a) * 128 + i * 8) = v;
}

// ---------------------------------------------------------------------------
// kGemmOut: out14[16384 x 14] (fp32) = [h_rnn, agg] @ W2p^T + b2.
__global__ __launch_bounds__(256) void kGemmOut(
    const bf* __restrict__ hrnn, const bf* __restrict__ aggB,
    const bf* __restrict__ W2p, const void* __restrict__ b2Raw,
    const int* __restrict__ flag, float* __restrict__ out) {
  const int tid = threadIdx.x;
  const int wave = tid >> 6, lane = tid & 63;
  const int quad = lane >> 4, ci = lane & 15;
  const int mr = blockIdx.x * 64 + wave * 16;
  const int f = *flag;

  float4v acc = {0.f, 0.f, 0.f, 0.f};
#pragma unroll
  for (int ks = 0; ks < 8; ++ks) {
    const bf* src = (ks < 4) ? hrnn : aggB;
    int k = (ks & 3) * 32 + quad * 8;
    short8 a = *(const short8*)(src + (size_t)(mr + ci) * 128 + k);
    short8 b = *(const short8*)(W2p + (size_t)ci * 256 + ks * 32 + quad * 8);
    acc = __builtin_amdgcn_mfma_f32_16x16x32_bf16(a, b, acc, 0, 0, 0);
  }

  if (ci < 14) {
    float bv = rdv(b2Raw, ci, f);
#pragma unroll
    for (int r = 0; r < 4; ++r)
      out[(size_t)(mr + quad * 4 + r) * 14 + ci] = acc[r] + bv;
  }
}

// ---------------------------------------------------------------------------
extern "C" void kernel_launch(void* const* d_in, const int* in_sizes, int n_in,
                              void* d_out, int out_size, void* d_ws, size_t ws_size,
                              hipStream_t stream) {
  const size_t OFF_ARENA = 0;          // bf16 arena; L (3.93MB) overlaps dead
                                       //   inputs+hidden [0, 8.38MB) after cell
  const size_t OFF_FLAG  = 10220544;
  const size_t OFF_A     = 10220800;   // x1+gi_c -> hw+agg
  const size_t OFF_WQK   = 26998016;   // 16 KB
  const size_t OFF_WCB   = 27014400;   // 1 KB
  const size_t OFF_W2P   = 27410944;   // 8 KB
  const size_t OFF_HRNN  = 27419136;   // 4 MB
  const size_t OFF_QK    = 31613440;   // 2 MB
  const size_t NEEDED    = 84042240;
  if (ws_size < NEEDED) return;
  if (n_in < 23 || in_sizes[0] != 2097152 || in_sizes[3] != 16384 ||
      in_sizes[5] != 49152 || in_sizes[9] != 98304 || in_sizes[17] != 512 ||
      in_sizes[19] != 4096 || in_sizes[21] != 3584 || out_size != 2326528)
    return;

  char* ws = (char*)d_ws;
  bf*    arena = (bf*)(ws + OFF_ARENA);
  float* L     = (float*)(ws + OFF_ARENA);  // 3.93 MB; valid after cell GRU
  int*   flag  = (int*)(ws + OFF_FLAG);
  bf*    x1    = (bf*)(ws + OFF_A);
  bf*    gi_c  = (bf*)(ws + OFF_A + 4194304);
  float* hw    = (float*)(ws + OFF_A);      // after kSeq (983 KB)
  bf*    aggB  = (bf*)(ws + OFF_A + 983040);
  bf*    Wqk   = (bf*)(ws + OFF_WQK);
  bf*    Wcb   = (bf*)(ws + OFF_WCB);
  bf*    W2p   = (bf*)(ws + OFF_W2P);
  bf*    hrnn  = (bf*)(ws + OFF_HRNN);
  bf*    qk    = (bf*)(ws + OFF_QK);

  float* out14 = (float*)d_out;
  float* outh  = (float*)d_out + 229376;

  kDetect<<<1, 1024, 0, stream>>>((const unsigned short*)d_in[0], flag);
  CArgs ca;
  for (int i = 0; i < 23; ++i) { ca.src[i] = d_in[i]; ca.n[i] = AN[i]; ca.off[i] = AO[i]; }
  kConvert<<<dim3(128, 23), 256, 0, stream>>>(ca, flag, arena);

  const bf* inputs = arena + AO[0];
  const bf* hidden = arena + AO[1];
  const bf* W1     = arena + AO[3];
  const bf* b1     = arena + AO[4];
  const bf* Wih_c  = arena + AO[5];
  const bf* Whh_c  = arena + AO[6];
  const bf* bih_c  = arena + AO[7];
  const bf* bhh_c  = arena + AO[8];
  const bf* Wih_f  = arena + AO[9];
  const bf* Whh_f  = arena + AO[10];
  const bf* bih_f  = arena + AO[11];
  const bf* bhh_f  = arena + AO[12];
  const bf* Wih_b  = arena + AO[13];
  const bf* Whh_b  = arena + AO[14];
  const bf* bih_b  = arena + AO[15];
  const bf* bhh_b  = arena + AO[16];
  const bf* WcA    = arena + AO[17];
  const bf* Wq     = arena + AO[19];
  const bf* Wk     = arena + AO[20];
  const bf* W2a    = arena + AO[21];

  kPrep<<<dim3(32), 256, 0, stream>>>(Wq, Wk, W2a, WcA, Wqk, W2p, Wcb);
  kGemm<<<dim3(256, 2), 256, 0, stream>>>(inputs, W1, b1, x1, 128, 1);
  kGemm<<<dim3(256, 6), 256, 0, stream>>>(x1, Wih_c, bih_c, gi_c, 384, 0);
  // cell GRU: h_rnn (bf16 + fp32 copy to d_out)
  kStep<<<dim3(256, 1, 2), 256, 0, stream>>>(hidden, Whh_c, gi_c, 384, bhh_c,
                                             hrnn, outh);
  // qk = h_rnn @ [Wq;Wk]^T  (16384 x 64)
  kGemm<<<dim3(256, 1), 256, 0, stream>>>(hrnn, Wqk, (const bf*)nullptr, qk, 64, 0);

  // fused gi-GEMM + 15-step bidirectional GRU -> L
  kSeq<<<dim3(1024, 2), 256, 0, stream>>>(hrnn, Wih_f, Wih_b, Whh_f, Whh_b,
                                          bih_f, bih_b, bhh_f, bhh_b, Wcb, L);

  kGumbel<<<dim3(960), 256, 0, stream>>>(L, d_in[2], flag, d_in[18], hw);
  kAttn<<<dim3(1024), 256, 0, stream>>>(hrnn, qk, hw, aggB);
  kGemmOut<<<dim3(256), 256, 0, stream>>>(hrnn, aggB, W2p, d_in[22], flag, out14);
}